// Round 4
// baseline (594.416 us; speedup 1.0000x reference)
//
#include <hip/hip_runtime.h>
#include <math.h>

#define C_DIM 256
#define HW_DIM 1024
#define N_DIM 64
#define M_TOTAL (N_DIM * HW_DIM)   // 65536
#define EPS_F 1e-5f

typedef __attribute__((ext_vector_type(8))) short short8;   // 8 bf16 (MFMA A/B frag)
typedef __attribute__((ext_vector_type(4))) float v4f;      // MFMA C/D frag
typedef __attribute__((ext_vector_type(4))) float f4;       // indexable float4

// fp32 -> bf16 round-to-nearest-even
__device__ __forceinline__ unsigned short f2bf(float x) {
    unsigned u = __float_as_uint(x);
    u = (u + 0x7FFFu + ((u >> 16) & 1u)) >> 16;
    return (unsigned short)u;
}
__device__ __forceinline__ float bf2f(unsigned short h) {
    return __uint_as_float(((unsigned)h) << 16);
}
__device__ __forceinline__ unsigned pack2(float lo, float hi) {
    return (unsigned)f2bf(lo) | ((unsigned)f2bf(hi) << 16);
}
// split f4 into hi (bf16 RNE) and lo (bf16 of residual): ~fp32 precision in 2 bf16
__device__ __forceinline__ void split4v(f4 v, uint2* hi, uint2* lo) {
    unsigned short h0 = f2bf(v[0]), h1 = f2bf(v[1]), h2 = f2bf(v[2]), h3 = f2bf(v[3]);
    float r0 = v[0] - bf2f(h0), r1 = v[1] - bf2f(h1), r2 = v[2] - bf2f(h2), r3 = v[3] - bf2f(h3);
    hi->x = (unsigned)h0 | ((unsigned)h1 << 16);
    hi->y = (unsigned)h2 | ((unsigned)h3 << 16);
    lo->x = (unsigned)f2bf(r0) | ((unsigned)f2bf(r1) << 16);
    lo->y = (unsigned)f2bf(r2) | ((unsigned)f2bf(r3) << 16);
}

// Coherent (LLC) 16B load: volatile lowers to sc0 sc1 on gfx940+ — bypasses
// L1/L2, reads the coherent Infinity Cache. No invalidates needed anywhere.
__device__ __forceinline__ f4 ldv4(const float* p) {
    return *(const volatile f4*)p;
}

// ---------------------------------------------------------------------------
// Fence-free grid barrier. Valid because ALL cross-block data in ns_persist
// is accessed volatile (sc0 sc1, write-through to LLC): once vmcnt==0, this
// wave's stores are agent-visible; no L2 writeback/invalidate required.
__device__ __forceinline__ void gsync(unsigned* bar, unsigned target) {
    asm volatile("s_waitcnt vmcnt(0)" ::: "memory");   // this wave's stores at LLC
    __syncthreads();                                   // all waves drained
    if (threadIdx.x == 0) {
        __hip_atomic_fetch_add(bar, 1u, __ATOMIC_RELAXED, __HIP_MEMORY_SCOPE_AGENT);
        while (__hip_atomic_load(bar, __ATOMIC_RELAXED, __HIP_MEMORY_SCOPE_AGENT) < target)
            __builtin_amdgcn_s_sleep(1);
    }
    __syncthreads();
}

// ---------------------------------------------------------------------------
// Kernel 1: Xbf = bf16(X) + per-channel sums (atomic). grid 4096, block 256.
__global__ void prepass_kernel(const float* __restrict__ X, unsigned short* __restrict__ Xbf,
                               float* __restrict__ musum) {
    int b = blockIdx.x;
    int t = threadIdx.x;
    int r = t >> 6;
    int l = t & 63;
    size_t row = (size_t)(4 * b + r);
    const float4* src = (const float4*)(X + (row << 10));
    uint2* dst = (uint2*)(Xbf + (row << 10));
    float s = 0.f;
#pragma unroll
    for (int j = 0; j < 4; ++j) {
        float4 v = src[l + 64 * j];
        uint2 p; p.x = pack2(v.x, v.y); p.y = pack2(v.z, v.w);
        dst[l + 64 * j] = p;
        s += v.x + v.y + v.z + v.w;
    }
    for (int off = 32; off > 0; off >>= 1) s += __shfl_down(s, off);
    if (l == 0) atomicAdd(&musum[(4 * b + r) & 255], s);
}

// ---------------------------------------------------------------------------
// Kernel 2: raw Gram G += X X^T via bf16 MFMA, symmetric (3 unique tiles).
// grid (3 tiles, 128 k-splits), block 512 (8 waves: 2x4 of 64x32).
__global__ __launch_bounds__(512, 3)
void gram_mfma(const unsigned short* __restrict__ Xbf, float* __restrict__ G) {
    int tile = blockIdx.x;               // 0:(0,0) 1:(0,128) 2:(128,128)
    int ci = (tile >> 1) * 128;
    int cj = (tile == 0) ? 0 : 128;
    int ks = blockIdx.y;                 // 0..127, K=512 each
    int t = threadIdx.x, wave = t >> 6, lane = t & 63;
    int wy = wave >> 2, wx = wave & 3;
    int quad = lane >> 4, l16 = lane & 15;

    __shared__ __align__(16) unsigned short As[128 * 72];
    __shared__ __align__(16) unsigned short Bs[128 * 72];
    const unsigned short* Bsrc = (ci == cj) ? As : Bs;

    v4f acc[4][2] = {};
    int n = ks >> 1;
    int hwbase = (ks & 1) * 512;
    const unsigned short* base = Xbf + (((size_t)n * C_DIM) << 10);
    int srow = t >> 2;
    int schunk = t & 3;

    for (int s = 0; s < 8; ++s) {
        int k0 = hwbase + s * 64;
        __syncthreads();
#pragma unroll
        for (int h = 0; h < 2; ++h) {
            int ch = schunk + 4 * h;
            *(uint4*)&As[srow * 72 + ch * 8] =
                *(const uint4*)&base[(((size_t)(ci + srow)) << 10) + k0 + ch * 8];
            if (ci != cj)
                *(uint4*)&Bs[srow * 72 + ch * 8] =
                    *(const uint4*)&base[(((size_t)(cj + srow)) << 10) + k0 + ch * 8];
        }
        __syncthreads();

        short8 af[4][2], bfr[2][2];
#pragma unroll
        for (int mt = 0; mt < 4; ++mt)
#pragma unroll
            for (int kh = 0; kh < 2; ++kh)
                af[mt][kh] = *(const short8*)&As[(64 * wy + 16 * mt + l16) * 72 + kh * 32 + quad * 8];
#pragma unroll
        for (int nt = 0; nt < 2; ++nt)
#pragma unroll
            for (int kh = 0; kh < 2; ++kh)
                bfr[nt][kh] = *(const short8*)&Bsrc[(32 * wx + 16 * nt + l16) * 72 + kh * 32 + quad * 8];
#pragma unroll
        for (int kh = 0; kh < 2; ++kh)
#pragma unroll
            for (int mt = 0; mt < 4; ++mt)
#pragma unroll
                for (int nt = 0; nt < 2; ++nt)
                    acc[mt][nt] = __builtin_amdgcn_mfma_f32_16x16x32_bf16(af[mt][kh], bfr[nt][kh], acc[mt][nt], 0, 0, 0);
    }

#pragma unroll
    for (int mt = 0; mt < 4; ++mt)
#pragma unroll
        for (int nt = 0; nt < 2; ++nt)
#pragma unroll
            for (int r = 0; r < 4; ++r) {
                int row = ci + 64 * wy + 16 * mt + 4 * quad + r;
                int col = cj + 32 * wx + 16 * nt + l16;
                atomicAdd(&G[row * C_DIM + col], acc[mt][nt][r]);
            }
}

// ---------------------------------------------------------------------------
// MFMA 64x64-tile matmul core, K=256, bf16 hi/lo split (~fp32 precision).
// REQUIRES: B symmetric (stages B rows as columns). block 256 (4 waves 2x2).
// All global loads volatile (sc0 sc1 -> LLC). Next-chunk prefetch issued
// before the MFMA cluster so LLC latency overlaps MFMA+epilogue.
__device__ __forceinline__ void mm_mfma64(const float* A, const float* B,
                                          int ci, int cj, v4f acc[2][2],
                                          unsigned short* Ah, unsigned short* Al,
                                          unsigned short* Bh, unsigned short* Bl) {
    int t = threadIdx.x, wave = t >> 6, lane = t & 63;
    int wy = wave >> 1, wx = wave & 1;
    int quad = lane >> 4, l16 = lane & 15;
    int row = t >> 2, cg_ = (t & 3) * 16;

    f4 va[4], vb[4];
#pragma unroll
    for (int i = 0; i < 4; ++i) {
        va[i] = ldv4(&A[(ci + row) * C_DIM + cg_ + 4 * i]);
        vb[i] = ldv4(&B[(cj + row) * C_DIM + cg_ + 4 * i]);
    }

    for (int kb = 0; kb < 256; kb += 64) {
        __syncthreads();
#pragma unroll
        for (int i = 0; i < 4; ++i) {
            uint2 hi, lo;
            split4v(va[i], &hi, &lo);
            *(uint2*)&Ah[row * 72 + cg_ + 4 * i] = hi;
            *(uint2*)&Al[row * 72 + cg_ + 4 * i] = lo;
            split4v(vb[i], &hi, &lo);
            *(uint2*)&Bh[row * 72 + cg_ + 4 * i] = hi;
            *(uint2*)&Bl[row * 72 + cg_ + 4 * i] = lo;
        }
        __syncthreads();

        short8 fah[2][2], fal[2][2], fbh[2][2], fbl[2][2];
#pragma unroll
        for (int mt = 0; mt < 2; ++mt)
#pragma unroll
            for (int kh = 0; kh < 2; ++kh) {
                int off = (32 * wy + 16 * mt + l16) * 72 + kh * 32 + quad * 8;
                fah[mt][kh] = *(const short8*)&Ah[off];
                fal[mt][kh] = *(const short8*)&Al[off];
            }
#pragma unroll
        for (int nt = 0; nt < 2; ++nt)
#pragma unroll
            for (int kh = 0; kh < 2; ++kh) {
                int off = (32 * wx + 16 * nt + l16) * 72 + kh * 32 + quad * 8;
                fbh[nt][kh] = *(const short8*)&Bh[off];
                fbl[nt][kh] = *(const short8*)&Bl[off];
            }
        // prefetch next K-chunk AFTER frag reads, BEFORE MFMAs: LLC latency
        // overlaps the MFMA cluster; drained at next iteration's barrier.
        if (kb < 192) {
#pragma unroll
            for (int i = 0; i < 4; ++i) {
                va[i] = ldv4(&A[(ci + row) * C_DIM + kb + 64 + cg_ + 4 * i]);
                vb[i] = ldv4(&B[(cj + row) * C_DIM + kb + 64 + cg_ + 4 * i]);
            }
        }
#pragma unroll
        for (int kh = 0; kh < 2; ++kh)
#pragma unroll
            for (int mt = 0; mt < 2; ++mt)
#pragma unroll
                for (int nt = 0; nt < 2; ++nt) {
                    acc[mt][nt] = __builtin_amdgcn_mfma_f32_16x16x32_bf16(fah[mt][kh], fbh[nt][kh], acc[mt][nt], 0, 0, 0);
                    acc[mt][nt] = __builtin_amdgcn_mfma_f32_16x16x32_bf16(fah[mt][kh], fbl[nt][kh], acc[mt][nt], 0, 0, 0);
                    acc[mt][nt] = __builtin_amdgcn_mfma_f32_16x16x32_bf16(fal[mt][kh], fbh[nt][kh], acc[mt][nt], 0, 0, 0);
                }
    }
}

// ---------------------------------------------------------------------------
// Persistent NS kernel: scal + init + 9 NS iterations + rot, fence-free barrier.
// REGULAR launch, 32 blocks x 256 threads (co-resident on 256 CUs).
// All P/Sig/T1/T2 traffic is volatile (sc0 sc1 -> coherent LLC).
__global__ __launch_bounds__(256, 1)
void ns_persist(const float* __restrict__ G, const float* __restrict__ musum,
                const float* __restrict__ R,
                float* Sig, float* P, float* T1, float* T2,
                unsigned short* __restrict__ Mbf, float* __restrict__ moff,
                unsigned* bar) {
    __shared__ __align__(16) unsigned short Ah[64 * 72];
    __shared__ __align__(16) unsigned short Al[64 * 72];
    __shared__ __align__(16) unsigned short Bh[64 * 72];
    __shared__ __align__(16) unsigned short Bl[64 * 72];
    __shared__ float red[256];
    __shared__ float scal_sh[2];

    int bid = blockIdx.x;
    int t = threadIdx.x;
    int wave = t >> 6, lane = t & 63;
    int wy = wave >> 1, wx = wave & 1, quad = lane >> 4, l16 = lane & 15;
    unsigned tg = 0;

    // ---- Phase 0: trace of Sigma (every block computes identical trr)
    {
        float mu = musum[t] * (1.0f / M_TOTAL);
        float d = G[t * (C_DIM + 1)] * (1.0f / M_TOTAL) - mu * mu + EPS_F;
        red[t] = d;
        __syncthreads();
        for (int off = 128; off > 0; off >>= 1) {
            if (t < off) red[t] += red[t + off];
            __syncthreads();
        }
        if (t == 0) {
            float trr = 1.0f / red[0];
            scal_sh[0] = trr;
            scal_sh[1] = sqrtf(trr);
        }
        __syncthreads();
    }
    float trr = scal_sh[0];
    float s1  = scal_sh[1];

    // ---- Phase 1: Sig = Sigma_N (mirrored symmetric), P = 1.5I - 0.5*Sig.
    {
        int base = bid * 2048 + t;
#pragma unroll
        for (int j = 0; j < 8; ++j) {
            int idx = base + j * 256;
            int r = idx >> 8, c = idx & 255;
            float g = (r >= 128 && c < 128) ? G[c * C_DIM + r] : G[idx];
            float mu_r = musum[r] * (1.0f / M_TOTAL);
            float mu_c = musum[c] * (1.0f / M_TOTAL);
            float sig = (g * (1.0f / M_TOTAL) - mu_r * mu_c + ((r == c) ? EPS_F : 0.f)) * trr;
            *(volatile float*)&Sig[idx] = sig;
            *(volatile float*)&P[idx] = ((r == c) ? 1.5f : 0.f) - 0.5f * sig;
        }
    }
    tg += 32; gsync(bar, tg);

    // ---- Phase 2: 9 Newton-Schulz iterations
    for (int it = 1; it < 10; ++it) {
        {   // A: 32 blocks, two independent matmuls
            int tb = bid & 15;
            int ci = (tb >> 2) * 64, cj = (tb & 3) * 64;
            const float* B = (bid < 16) ? P : Sig;
            float* D = (bid < 16) ? T1 : T2;
            v4f acc[2][2] = {};
            mm_mfma64(P, B, ci, cj, acc, Ah, Al, Bh, Bl);
#pragma unroll
            for (int mt = 0; mt < 2; ++mt)
#pragma unroll
                for (int nt = 0; nt < 2; ++nt)
#pragma unroll
                    for (int r = 0; r < 4; ++r) {
                        int rr = ci + 32 * wy + 16 * mt + 4 * quad + r;
                        int cc = cj + 32 * wx + 16 * nt + l16;
                        *(volatile float*)&D[rr * C_DIM + cc] = acc[mt][nt][r];
                    }
        }
        tg += 32; gsync(bar, tg);
        if (bid < 16) {  // B: P = 1.5P - 0.5*(T1@T2)   (T2 symmetric: P,Sig commute)
            int ci = (bid >> 2) * 64, cj = (bid & 3) * 64;
            v4f acc[2][2] = {};
            mm_mfma64(T1, T2, ci, cj, acc, Ah, Al, Bh, Bl);
#pragma unroll
            for (int mt = 0; mt < 2; ++mt)
#pragma unroll
                for (int nt = 0; nt < 2; ++nt)
#pragma unroll
                    for (int r = 0; r < 4; ++r) {
                        int rr = ci + 32 * wy + 16 * mt + 4 * quad + r;
                        int cc = cj + 32 * wx + 16 * nt + l16;
                        int idx = rr * C_DIM + cc;
                        float pv = *(const volatile float*)&P[idx];
                        *(volatile float*)&P[idx] = 1.5f * pv - 0.5f * acc[mt][nt][r];
                    }
        }
        tg += 32; gsync(bar, tg);
    }

    // ---- Phase 3: rot. M = (R@P)*s1 -> Mbf (bf16) + moff[d] = dot(M[d,:], mu).
    if (bid < 16) {
        int ci = (bid >> 2) * 64, cj = (bid & 3) * 64;
        v4f acc[2][2] = {};
        mm_mfma64(R, P, ci, cj, acc, Ah, Al, Bh, Bl);

        float muc[2];
#pragma unroll
        for (int nt = 0; nt < 2; ++nt)
            muc[nt] = musum[cj + 32 * wx + 16 * nt + l16] * (1.0f / M_TOTAL);
#pragma unroll
        for (int mt = 0; mt < 2; ++mt)
#pragma unroll
            for (int r = 0; r < 4; ++r) {
                int rr = ci + 32 * wy + 16 * mt + 4 * quad + r;
                float s = 0.f;
#pragma unroll
                for (int nt = 0; nt < 2; ++nt) {
                    float val = acc[mt][nt][r] * s1;
                    Mbf[rr * C_DIM + cj + 32 * wx + 16 * nt + l16] = f2bf(val);
                    s += val * muc[nt];
                }
                s += __shfl_xor(s, 1); s += __shfl_xor(s, 2);
                s += __shfl_xor(s, 4); s += __shfl_xor(s, 8);
                if (l16 == 0) atomicAdd(&moff[rr], s);
            }
    }
}

// ---------------------------------------------------------------------------
// Kernel 6: out[n,d,hw] = sum_c Mbf[d,c]*Xbf[n,c,hw] - moff[d]  via MFMA.
// grid: (8 hw-tiles, 2 d-tiles, 64 n), block 256 (4 waves of 64x64).
// Epilogue: LDS transpose -> float4 coalesced stores (full 128B lines).
__global__ void out_mfma(const unsigned short* __restrict__ Xbf,
                         const unsigned short* __restrict__ Mbf,
                         const float* __restrict__ moff, float* __restrict__ out) {
    int hwb = blockIdx.x * 128;
    int db  = blockIdx.y * 128;
    int n   = blockIdx.z;
    int t = threadIdx.x, wave = t >> 6, lane = t & 63;
    int wy = wave >> 1, wx = wave & 1, quad = lane >> 4, l16 = lane & 15;

    __shared__ __align__(16) unsigned short Asm[128 * 40];
    __shared__ __align__(16) unsigned short Bsm[128 * 34];
    __shared__ __align__(16) float Ep[4 * 16 * 68];   // per-wave 16x64 epilogue buffer

    v4f acc[4][4] = {};
    const unsigned short* Xn = Xbf + (((size_t)n * C_DIM) << 10);

    for (int kb = 0; kb < 256; kb += 32) {
        __syncthreads();
#pragma unroll
        for (int i = 0; i < 2; ++i) {
            int a = t + 256 * i;
            int row = a >> 2, c8 = a & 3;
            *(uint4*)(&Asm[row * 40 + 8 * c8]) =
                *(const uint4*)(&Mbf[(db + row) * C_DIM + kb + 8 * c8]);
        }
#pragma unroll
        for (int i = 0; i < 16; ++i) {
            int idx = t + 256 * i;
            int hw = idx & 127, crow = idx >> 7;
            Bsm[hw * 34 + crow] = Xn[(((size_t)(kb + crow)) << 10) + hwb + hw];
        }
        __syncthreads();

        short8 af[4], bfr[4];
#pragma unroll
        for (int mt = 0; mt < 4; ++mt)
            af[mt] = *(const short8*)(&Asm[(64 * wy + 16 * mt + l16) * 40 + 8 * quad]);
#pragma unroll
        for (int nt = 0; nt < 4; ++nt) {
            union { short8 s; unsigned u[4]; } tmp;
            const unsigned short* bp = &Bsm[(64 * wx + 16 * nt + l16) * 34 + 8 * quad];
            tmp.u[0] = *(const unsigned*)(bp + 0);
            tmp.u[1] = *(const unsigned*)(bp + 2);
            tmp.u[2] = *(const unsigned*)(bp + 4);
            tmp.u[3] = *(const unsigned*)(bp + 6);
            bfr[nt] = tmp.s;
        }
#pragma unroll
        for (int mt = 0; mt < 4; ++mt)
#pragma unroll
            for (int nt = 0; nt < 4; ++nt)
                acc[mt][nt] = __builtin_amdgcn_mfma_f32_16x16x32_bf16(af[mt], bfr[nt], acc[mt][nt], 0, 0, 0);
    }

    float* W = &Ep[wave * 16 * 68];
#pragma unroll
    for (int mt = 0; mt < 4; ++mt) {
        // dump this wave's 16x64 tile (row = 4*quad+r, col = 16*nt+l16), moff folded in
#pragma unroll
        for (int r = 0; r < 4; ++r) {
            float off = moff[db + 64 * wy + 16 * mt + 4 * quad + r];
#pragma unroll
            for (int nt = 0; nt < 4; ++nt)
                W[(4 * quad + r) * 68 + 16 * nt + l16] = acc[mt][nt][r] - off;
        }
        __syncthreads();   // orders wave-local LDS ops; uniform across block
        // read back transposed-in-lane: 16 lanes x float4 = 256B contiguous per row
#pragma unroll
        for (int j = 0; j < 4; ++j) {
            int row = 4 * j + quad;
            float4 v = *(const float4*)&W[row * 68 + 4 * l16];
            int d = db + 64 * wy + 16 * mt + row;
            int hw = hwb + 64 * wx + 4 * l16;
            *(float4*)&out[(((size_t)(n * C_DIM + d)) << 10) + hw] = v;
        }
        __syncthreads();
    }
}

// ---------------------------------------------------------------------------
extern "C" void kernel_launch(void* const* d_in, const int* in_sizes, int n_in,
                              void* d_out, int out_size, void* d_ws, size_t ws_size,
                              hipStream_t stream) {
    const float* X = (const float*)d_in[0];        // (64,256,32,32)
    const float* R = (const float*)d_in[1];        // (1,256,256)
    float* out = (float*)d_out;
    float* ws  = (float*)d_ws;

    float* musum = ws;                         // 256
    unsigned* bar = (unsigned*)(ws + 256);     // barrier counter (zeroed by memset)
    float* moff  = ws + 272;                   // 256
    float* G     = ws + 528;                   // 65536 (raw gram, 3 tiles)
    float* Sig   = G + 65536;                  // Sigma_N fp32 (symmetric)
    float* P     = Sig + 65536;
    float* T1    = P + 65536;
    float* T2    = T1 + 65536;
    unsigned short* Mbf = (unsigned short*)(T2 + 65536);   // 65536 ushort
    unsigned short* Xbf = Mbf + 65536;                     // 16M ushort (32 MB)

    hipMemsetAsync(ws, 0, (528 + 65536) * sizeof(float), stream);

    prepass_kernel<<<4096, 256, 0, stream>>>(X, Xbf, musum);
    gram_mfma<<<dim3(3, 128), 512, 0, stream>>>(Xbf, G);

    ns_persist<<<32, 256, 0, stream>>>(G, musum, R, Sig, P, T1, T2, Mbf, moff, bar);

    out_mfma<<<dim3(8, 2, 64), 256, 0, stream>>>(Xbf, Mbf, moff, out);
}

// Round 8
// 431.653 us; speedup vs baseline: 1.3771x; 1.3771x over previous
//
#include <hip/hip_runtime.h>
#include <math.h>

#define C_DIM 256
#define HW_DIM 1024
#define N_DIM 64
#define M_TOTAL (N_DIM * HW_DIM)   // 65536
#define EPS_F 1e-5f
#define LDK 264                     // LDS row stride (256 + 8 pad), shorts

typedef __attribute__((ext_vector_type(8))) short short8;   // 8 bf16 (MFMA A/B frag)
typedef __attribute__((ext_vector_type(4))) float v4f;      // MFMA C/D frag
typedef __attribute__((ext_vector_type(4))) float f4;       // indexable float4

// fp32 -> bf16 round-to-nearest-even
__device__ __forceinline__ unsigned short f2bf(float x) {
    unsigned u = __float_as_uint(x);
    u = (u + 0x7FFFu + ((u >> 16) & 1u)) >> 16;
    return (unsigned short)u;
}
__device__ __forceinline__ float bf2f(unsigned short h) {
    return __uint_as_float(((unsigned)h) << 16);
}
__device__ __forceinline__ unsigned pack2(float lo, float hi) {
    return (unsigned)f2bf(lo) | ((unsigned)f2bf(hi) << 16);
}
// split f4 into hi (bf16 RNE) and lo (bf16 of residual): ~fp32 precision in 2 bf16
__device__ __forceinline__ void split4v(f4 v, uint2* hi, uint2* lo) {
    unsigned short h0 = f2bf(v[0]), h1 = f2bf(v[1]), h2 = f2bf(v[2]), h3 = f2bf(v[3]);
    float r0 = v[0] - bf2f(h0), r1 = v[1] - bf2f(h1), r2 = v[2] - bf2f(h2), r3 = v[3] - bf2f(h3);
    hi->x = (unsigned)h0 | ((unsigned)h1 << 16);
    hi->y = (unsigned)h2 | ((unsigned)h3 << 16);
    lo->x = (unsigned)f2bf(r0) | ((unsigned)f2bf(r1) << 16);
    lo->y = (unsigned)f2bf(r2) | ((unsigned)f2bf(r3) << 16);
}

// ---------------------------------------------------------------------------
// Grid barrier with explicit minimal cache maintenance (32 co-resident blocks).
// Release: wbl2 (write back dirty L2 lines -> LLC; dirty footprint ~32KB/XCD)
//          + vmcnt(0), then counter add (agent scope, LLC-resident).
// Acquire: spin on counter, then buffer_inv sc1 (invalidate L1+L2) so
//          subsequent loads refetch from LLC. Normal cached loads/stores
//          everywhere else — no volatile serialization.
__device__ __forceinline__ void gsync(unsigned* bar, unsigned target) {
    asm volatile("buffer_wbl2 sc1" ::: "memory");
    asm volatile("s_waitcnt vmcnt(0)" ::: "memory");
    __syncthreads();
    if (threadIdx.x == 0) {
        __hip_atomic_fetch_add(bar, 1u, __ATOMIC_RELAXED, __HIP_MEMORY_SCOPE_AGENT);
        while (__hip_atomic_load(bar, __ATOMIC_RELAXED, __HIP_MEMORY_SCOPE_AGENT) < target)
            __builtin_amdgcn_s_sleep(1);
    }
    __syncthreads();
    asm volatile("buffer_inv sc1" ::: "memory");
    asm volatile("s_waitcnt vmcnt(0)" ::: "memory");
}

// ---------------------------------------------------------------------------
// Kernel 1: Xbf = bf16(X) + per-channel sums (atomic). grid 4096, block 256.
__global__ void prepass_kernel(const float* __restrict__ X, unsigned short* __restrict__ Xbf,
                               float* __restrict__ musum) {
    int b = blockIdx.x;
    int t = threadIdx.x;
    int r = t >> 6;
    int l = t & 63;
    size_t row = (size_t)(4 * b + r);
    const float4* src = (const float4*)(X + (row << 10));
    uint2* dst = (uint2*)(Xbf + (row << 10));
    float s = 0.f;
#pragma unroll
    for (int j = 0; j < 4; ++j) {
        float4 v = src[l + 64 * j];
        uint2 p; p.x = pack2(v.x, v.y); p.y = pack2(v.z, v.w);
        dst[l + 64 * j] = p;
        s += v.x + v.y + v.z + v.w;
    }
    for (int off = 32; off > 0; off >>= 1) s += __shfl_down(s, off);
    if (l == 0) atomicAdd(&musum[(4 * b + r) & 255], s);
}

// ---------------------------------------------------------------------------
// Kernel 2: raw Gram G += X X^T via bf16 MFMA, symmetric (3 unique tiles).
// grid (3 tiles, 128 k-splits), block 512 (8 waves: 2x4 of 64x32).
__global__ __launch_bounds__(512, 3)
void gram_mfma(const unsigned short* __restrict__ Xbf, float* __restrict__ G) {
    int tile = blockIdx.x;               // 0:(0,0) 1:(0,128) 2:(128,128)
    int ci = (tile >> 1) * 128;
    int cj = (tile == 0) ? 0 : 128;
    int ks = blockIdx.y;                 // 0..127, K=512 each
    int t = threadIdx.x, wave = t >> 6, lane = t & 63;
    int wy = wave >> 2, wx = wave & 3;
    int quad = lane >> 4, l16 = lane & 15;

    __shared__ __align__(16) unsigned short As[128 * 72];
    __shared__ __align__(16) unsigned short Bs[128 * 72];
    const unsigned short* Bsrc = (ci == cj) ? As : Bs;

    v4f acc[4][2] = {};
    int n = ks >> 1;
    int hwbase = (ks & 1) * 512;
    const unsigned short* base = Xbf + (((size_t)n * C_DIM) << 10);
    int srow = t >> 2;
    int schunk = t & 3;

    for (int s = 0; s < 8; ++s) {
        int k0 = hwbase + s * 64;
        __syncthreads();
#pragma unroll
        for (int h = 0; h < 2; ++h) {
            int ch = schunk + 4 * h;
            *(uint4*)&As[srow * 72 + ch * 8] =
                *(const uint4*)&base[(((size_t)(ci + srow)) << 10) + k0 + ch * 8];
            if (ci != cj)
                *(uint4*)&Bs[srow * 72 + ch * 8] =
                    *(const uint4*)&base[(((size_t)(cj + srow)) << 10) + k0 + ch * 8];
        }
        __syncthreads();

        short8 af[4][2], bfr[2][2];
#pragma unroll
        for (int mt = 0; mt < 4; ++mt)
#pragma unroll
            for (int kh = 0; kh < 2; ++kh)
                af[mt][kh] = *(const short8*)&As[(64 * wy + 16 * mt + l16) * 72 + kh * 32 + quad * 8];
#pragma unroll
        for (int nt = 0; nt < 2; ++nt)
#pragma unroll
            for (int kh = 0; kh < 2; ++kh)
                bfr[nt][kh] = *(const short8*)&Bsrc[(32 * wx + 16 * nt + l16) * 72 + kh * 32 + quad * 8];
#pragma unroll
        for (int kh = 0; kh < 2; ++kh)
#pragma unroll
            for (int mt = 0; mt < 4; ++mt)
#pragma unroll
                for (int nt = 0; nt < 2; ++nt)
                    acc[mt][nt] = __builtin_amdgcn_mfma_f32_16x16x32_bf16(af[mt][kh], bfr[nt][kh], acc[mt][nt], 0, 0, 0);
    }

#pragma unroll
    for (int mt = 0; mt < 4; ++mt)
#pragma unroll
        for (int nt = 0; nt < 2; ++nt)
#pragma unroll
            for (int r = 0; r < 4; ++r) {
                int row = ci + 64 * wy + 16 * mt + 4 * quad + r;
                int col = cj + 32 * wx + 16 * nt + l16;
                atomicAdd(&G[row * C_DIM + col], acc[mt][nt][r]);
            }
}

// ---------------------------------------------------------------------------
// MFMA 64x64-tile matmul core, K=256, bf16 hi/lo split (~fp32 precision).
// REQUIRES: B symmetric (stages B rows as columns). block 256 (4 waves 2x2).
// Burst version: loads the FULL 64x256 A and B panels into registers with all
// loads in flight (one latency exposure), converts into a full-K LDS image,
// then all 4 K-chunks run from LDS with a single __syncthreads.
__device__ __forceinline__ void mm_mfma64(const float* __restrict__ A, const float* __restrict__ B,
                                          int ci, int cj, v4f acc[2][2],
                                          unsigned short* Ah, unsigned short* Al,
                                          unsigned short* Bh, unsigned short* Bl) {
    int t = threadIdx.x, wave = t >> 6, lane = t & 63;
    int wy = wave >> 1, wx = wave & 1;
    int quad = lane >> 4, l16 = lane & 15;
    int row = t >> 2, cg_ = (t & 3) * 16;   // row 0..63, col-group base {0,16,32,48}

    // Burst: 16 + 16 dwordx4 loads, all outstanding together.
    f4 va[16], vb[16];
#pragma unroll
    for (int j = 0; j < 4; ++j)
#pragma unroll
        for (int i = 0; i < 4; ++i)
            va[4 * j + i] = *(const f4*)&A[(ci + row) * C_DIM + 64 * j + cg_ + 4 * i];
#pragma unroll
    for (int j = 0; j < 4; ++j)
#pragma unroll
        for (int i = 0; i < 4; ++i)
            vb[4 * j + i] = *(const f4*)&B[(cj + row) * C_DIM + 64 * j + cg_ + 4 * i];

#pragma unroll
    for (int j = 0; j < 16; ++j) {
        uint2 hi, lo;
        int col = 64 * (j >> 2) + cg_ + 4 * (j & 3);
        split4v(va[j], &hi, &lo);
        *(uint2*)&Ah[row * LDK + col] = hi;
        *(uint2*)&Al[row * LDK + col] = lo;
    }
#pragma unroll
    for (int j = 0; j < 16; ++j) {
        uint2 hi, lo;
        int col = 64 * (j >> 2) + cg_ + 4 * (j & 3);
        split4v(vb[j], &hi, &lo);
        *(uint2*)&Bh[row * LDK + col] = hi;
        *(uint2*)&Bl[row * LDK + col] = lo;
    }
    __syncthreads();

    for (int kb = 0; kb < 256; kb += 64) {
        short8 fah[2][2], fal[2][2], fbh[2][2], fbl[2][2];
#pragma unroll
        for (int mt = 0; mt < 2; ++mt)
#pragma unroll
            for (int kh = 0; kh < 2; ++kh) {
                int off = (32 * wy + 16 * mt + l16) * LDK + kb + kh * 32 + quad * 8;
                fah[mt][kh] = *(const short8*)&Ah[off];
                fal[mt][kh] = *(const short8*)&Al[off];
            }
#pragma unroll
        for (int nt = 0; nt < 2; ++nt)
#pragma unroll
            for (int kh = 0; kh < 2; ++kh) {
                int off = (32 * wx + 16 * nt + l16) * LDK + kb + kh * 32 + quad * 8;
                fbh[nt][kh] = *(const short8*)&Bh[off];
                fbl[nt][kh] = *(const short8*)&Bl[off];
            }
#pragma unroll
        for (int kh = 0; kh < 2; ++kh)
#pragma unroll
            for (int mt = 0; mt < 2; ++mt)
#pragma unroll
                for (int nt = 0; nt < 2; ++nt) {
                    acc[mt][nt] = __builtin_amdgcn_mfma_f32_16x16x32_bf16(fah[mt][kh], fbh[nt][kh], acc[mt][nt], 0, 0, 0);
                    acc[mt][nt] = __builtin_amdgcn_mfma_f32_16x16x32_bf16(fah[mt][kh], fbl[nt][kh], acc[mt][nt], 0, 0, 0);
                    acc[mt][nt] = __builtin_amdgcn_mfma_f32_16x16x32_bf16(fal[mt][kh], fbh[nt][kh], acc[mt][nt], 0, 0, 0);
                }
    }
    // NOTE: LDS reuse across phases is ordered by the caller's gsync (__syncthreads).
}

// ---------------------------------------------------------------------------
// Persistent NS kernel: scal + init + 9 NS iterations + rot, custom barrier.
// REGULAR launch, 32 blocks x 256 threads (co-resident on 256 CUs).
// LDS: full-K hi/lo images, 4 x 64x264 shorts = 132 KB (1 block/CU, fine).
__global__ __launch_bounds__(256, 1)
void ns_persist(const float* __restrict__ G, const float* __restrict__ musum,
                const float* __restrict__ R,
                float* __restrict__ Sig, float* __restrict__ P,
                float* __restrict__ T1, float* __restrict__ T2,
                unsigned short* __restrict__ Mbf, float* __restrict__ moff,
                unsigned* bar) {
    __shared__ __align__(16) unsigned short Ah[64 * LDK];
    __shared__ __align__(16) unsigned short Al[64 * LDK];
    __shared__ __align__(16) unsigned short Bh[64 * LDK];
    __shared__ __align__(16) unsigned short Bl[64 * LDK];
    __shared__ float red[256];
    __shared__ float scal_sh[2];

    int bid = blockIdx.x;
    int t = threadIdx.x;
    int wave = t >> 6, lane = t & 63;
    int wy = wave >> 1, wx = wave & 1, quad = lane >> 4, l16 = lane & 15;
    unsigned tg = 0;

    // ---- Phase 0: trace of Sigma (every block computes identical trr)
    {
        float mu = musum[t] * (1.0f / M_TOTAL);
        float d = G[t * (C_DIM + 1)] * (1.0f / M_TOTAL) - mu * mu + EPS_F;
        red[t] = d;
        __syncthreads();
        for (int off = 128; off > 0; off >>= 1) {
            if (t < off) red[t] += red[t + off];
            __syncthreads();
        }
        if (t == 0) {
            float trr = 1.0f / red[0];
            scal_sh[0] = trr;
            scal_sh[1] = sqrtf(trr);
        }
        __syncthreads();
    }
    float trr = scal_sh[0];
    float s1  = scal_sh[1];

    // ---- Phase 1: Sig = Sigma_N (mirrored symmetric), P = 1.5I - 0.5*Sig.
    {
        int base = bid * 2048 + t;
#pragma unroll
        for (int j = 0; j < 8; ++j) {
            int idx = base + j * 256;
            int r = idx >> 8, c = idx & 255;
            float g = (r >= 128 && c < 128) ? G[c * C_DIM + r] : G[idx];
            float mu_r = musum[r] * (1.0f / M_TOTAL);
            float mu_c = musum[c] * (1.0f / M_TOTAL);
            float sig = (g * (1.0f / M_TOTAL) - mu_r * mu_c + ((r == c) ? EPS_F : 0.f)) * trr;
            Sig[idx] = sig;
            P[idx] = ((r == c) ? 1.5f : 0.f) - 0.5f * sig;
        }
    }
    tg += 32; gsync(bar, tg);

    // ---- Phase 2: 9 Newton-Schulz iterations
    for (int it = 1; it < 10; ++it) {
        {   // A: 32 blocks, two independent matmuls
            int tb = bid & 15;
            int ci = (tb >> 2) * 64, cj = (tb & 3) * 64;
            const float* B = (bid < 16) ? P : Sig;
            float* D = (bid < 16) ? T1 : T2;
            v4f acc[2][2] = {};
            mm_mfma64(P, B, ci, cj, acc, Ah, Al, Bh, Bl);
#pragma unroll
            for (int mt = 0; mt < 2; ++mt)
#pragma unroll
                for (int nt = 0; nt < 2; ++nt)
#pragma unroll
                    for (int r = 0; r < 4; ++r) {
                        int rr = ci + 32 * wy + 16 * mt + 4 * quad + r;
                        int cc = cj + 32 * wx + 16 * nt + l16;
                        D[rr * C_DIM + cc] = acc[mt][nt][r];
                    }
        }
        tg += 32; gsync(bar, tg);
        if (bid < 16) {  // B: P = 1.5P - 0.5*(T1@T2)   (T2 symmetric: P,Sig commute)
            int ci = (bid >> 2) * 64, cj = (bid & 3) * 64;
            v4f acc[2][2] = {};
            mm_mfma64(T1, T2, ci, cj, acc, Ah, Al, Bh, Bl);
#pragma unroll
            for (int mt = 0; mt < 2; ++mt)
#pragma unroll
                for (int nt = 0; nt < 2; ++nt)
#pragma unroll
                    for (int r = 0; r < 4; ++r) {
                        int rr = ci + 32 * wy + 16 * mt + 4 * quad + r;
                        int cc = cj + 32 * wx + 16 * nt + l16;
                        int idx = rr * C_DIM + cc;
                        P[idx] = 1.5f * P[idx] - 0.5f * acc[mt][nt][r];
                    }
        }
        tg += 32; gsync(bar, tg);
    }

    // ---- Phase 3: rot. M = (R@P)*s1 -> Mbf (bf16) + moff[d] = dot(M[d,:], mu).
    if (bid < 16) {
        int ci = (bid >> 2) * 64, cj = (bid & 3) * 64;
        v4f acc[2][2] = {};
        mm_mfma64(R, P, ci, cj, acc, Ah, Al, Bh, Bl);

        float muc[2];
#pragma unroll
        for (int nt = 0; nt < 2; ++nt)
            muc[nt] = musum[cj + 32 * wx + 16 * nt + l16] * (1.0f / M_TOTAL);
#pragma unroll
        for (int mt = 0; mt < 2; ++mt)
#pragma unroll
            for (int r = 0; r < 4; ++r) {
                int rr = ci + 32 * wy + 16 * mt + 4 * quad + r;
                float s = 0.f;
#pragma unroll
                for (int nt = 0; nt < 2; ++nt) {
                    float val = acc[mt][nt][r] * s1;
                    Mbf[rr * C_DIM + cj + 32 * wx + 16 * nt + l16] = f2bf(val);
                    s += val * muc[nt];
                }
                s += __shfl_xor(s, 1); s += __shfl_xor(s, 2);
                s += __shfl_xor(s, 4); s += __shfl_xor(s, 8);
                if (l16 == 0) atomicAdd(&moff[rr], s);
            }
    }
}

// ---------------------------------------------------------------------------
// Kernel 6: out[n,d,hw] = sum_c Mbf[d,c]*Xbf[n,c,hw] - moff[d]  via MFMA.
// grid: (8 hw-tiles, 2 d-tiles, 64 n), block 256 (4 waves of 64x64).
// Epilogue: LDS transpose -> float4 coalesced stores (full 128B lines).
__global__ void out_mfma(const unsigned short* __restrict__ Xbf,
                         const unsigned short* __restrict__ Mbf,
                         const float* __restrict__ moff, float* __restrict__ out) {
    int hwb = blockIdx.x * 128;
    int db  = blockIdx.y * 128;
    int n   = blockIdx.z;
    int t = threadIdx.x, wave = t >> 6, lane = t & 63;
    int wy = wave >> 1, wx = wave & 1, quad = lane >> 4, l16 = lane & 15;

    __shared__ __align__(16) unsigned short Asm[128 * 40];
    __shared__ __align__(16) unsigned short Bsm[128 * 34];
    __shared__ __align__(16) float Ep[4 * 16 * 68];   // per-wave 16x64 epilogue buffer

    v4f acc[4][4] = {};
    const unsigned short* Xn = Xbf + (((size_t)n * C_DIM) << 10);

    for (int kb = 0; kb < 256; kb += 32) {
        __syncthreads();
#pragma unroll
        for (int i = 0; i < 2; ++i) {
            int a = t + 256 * i;
            int row = a >> 2, c8 = a & 3;
            *(uint4*)(&Asm[row * 40 + 8 * c8]) =
                *(const uint4*)(&Mbf[(db + row) * C_DIM + kb + 8 * c8]);
        }
#pragma unroll
        for (int i = 0; i < 16; ++i) {
            int idx = t + 256 * i;
            int hw = idx & 127, crow = idx >> 7;
            Bsm[hw * 34 + crow] = Xn[(((size_t)(kb + crow)) << 10) + hwb + hw];
        }
        __syncthreads();

        short8 af[4], bfr[4];
#pragma unroll
        for (int mt = 0; mt < 4; ++mt)
            af[mt] = *(const short8*)(&Asm[(64 * wy + 16 * mt + l16) * 40 + 8 * quad]);
#pragma unroll
        for (int nt = 0; nt < 4; ++nt) {
            union { short8 s; unsigned u[4]; } tmp;
            const unsigned short* bp = &Bsm[(64 * wx + 16 * nt + l16) * 34 + 8 * quad];
            tmp.u[0] = *(const unsigned*)(bp + 0);
            tmp.u[1] = *(const unsigned*)(bp + 2);
            tmp.u[2] = *(const unsigned*)(bp + 4);
            tmp.u[3] = *(const unsigned*)(bp + 6);
            bfr[nt] = tmp.s;
        }
#pragma unroll
        for (int mt = 0; mt < 4; ++mt)
#pragma unroll
            for (int nt = 0; nt < 4; ++nt)
                acc[mt][nt] = __builtin_amdgcn_mfma_f32_16x16x32_bf16(af[mt], bfr[nt], acc[mt][nt], 0, 0, 0);
    }

    float* W = &Ep[wave * 16 * 68];
#pragma unroll
    for (int mt = 0; mt < 4; ++mt) {
        // dump this wave's 16x64 tile (row = 4*quad+r, col = 16*nt+l16), moff folded in
#pragma unroll
        for (int r = 0; r < 4; ++r) {
            float off = moff[db + 64 * wy + 16 * mt + 4 * quad + r];
#pragma unroll
            for (int nt = 0; nt < 4; ++nt)
                W[(4 * quad + r) * 68 + 16 * nt + l16] = acc[mt][nt][r] - off;
        }
        __syncthreads();   // orders wave-local LDS ops; uniform across block
        // read back transposed-in-lane: 16 lanes x float4 = 256B contiguous per row
#pragma unroll
        for (int j = 0; j < 4; ++j) {
            int row = 4 * j + quad;
            float4 v = *(const float4*)&W[row * 68 + 4 * l16];
            int d = db + 64 * wy + 16 * mt + row;
            int hw = hwb + 64 * wx + 4 * l16;
            *(float4*)&out[(((size_t)(n * C_DIM + d)) << 10) + hw] = v;
        }
        __syncthreads();
    }
}

// ---------------------------------------------------------------------------
extern "C" void kernel_launch(void* const* d_in, const int* in_sizes, int n_in,
                              void* d_out, int out_size, void* d_ws, size_t ws_size,
                              hipStream_t stream) {
    const float* X = (const float*)d_in[0];        // (64,256,32,32)
    const float* R = (const float*)d_in[1];        // (1,256,256)
    float* out = (float*)d_out;
    float* ws  = (float*)d_ws;

    float* musum = ws;                         // 256
    unsigned* bar = (unsigned*)(ws + 256);     // barrier counter (zeroed by memset)
    float* moff  = ws + 272;                   // 256
    float* G     = ws + 528;                   // 65536 (raw gram, 3 tiles)
    float* Sig   = G + 65536;                  // Sigma_N fp32 (symmetric)
    float* P     = Sig + 65536;
    float* T1    = P + 65536;
    float* T2    = T1 + 65536;
    unsigned short* Mbf = (unsigned short*)(T2 + 65536);   // 65536 ushort
    unsigned short* Xbf = Mbf + 65536;                     // 16M ushort (32 MB)

    hipMemsetAsync(ws, 0, (528 + 65536) * sizeof(float), stream);

    prepass_kernel<<<4096, 256, 0, stream>>>(X, Xbf, musum);
    gram_mfma<<<dim3(3, 128), 512, 0, stream>>>(Xbf, G);

    ns_persist<<<32, 256, 0, stream>>>(G, musum, R, Sig, P, T1, T2, Mbf, moff, bar);

    out_mfma<<<dim3(8, 2, 64), 256, 0, stream>>>(Xbf, Mbf, moff, out);
}

// Round 9
// 417.644 us; speedup vs baseline: 1.4233x; 1.0335x over previous
//
#include <hip/hip_runtime.h>
#include <math.h>

#define C_DIM 256
#define HW_DIM 1024
#define N_DIM 64
#define M_TOTAL (N_DIM * HW_DIM)   // 65536
#define EPS_F 1e-5f
#define LDK 264                     // LDS row stride (256 + 8 pad), shorts

typedef __attribute__((ext_vector_type(8))) short short8;   // 8 bf16 (MFMA A/B frag)
typedef __attribute__((ext_vector_type(4))) float v4f;      // MFMA C/D frag
typedef __attribute__((ext_vector_type(4))) float f4;       // indexable float4

// fp32 -> bf16 round-to-nearest-even
__device__ __forceinline__ unsigned short f2bf(float x) {
    unsigned u = __float_as_uint(x);
    u = (u + 0x7FFFu + ((u >> 16) & 1u)) >> 16;
    return (unsigned short)u;
}
__device__ __forceinline__ float bf2f(unsigned short h) {
    return __uint_as_float(((unsigned)h) << 16);
}
__device__ __forceinline__ unsigned pack2(float lo, float hi) {
    return (unsigned)f2bf(lo) | ((unsigned)f2bf(hi) << 16);
}
// split f4 into hi (bf16 RNE) and lo (bf16 of residual): ~fp32 precision in 2 bf16
__device__ __forceinline__ void split4v(f4 v, uint2* hi, uint2* lo) {
    unsigned short h0 = f2bf(v[0]), h1 = f2bf(v[1]), h2 = f2bf(v[2]), h3 = f2bf(v[3]);
    float r0 = v[0] - bf2f(h0), r1 = v[1] - bf2f(h1), r2 = v[2] - bf2f(h2), r3 = v[3] - bf2f(h3);
    hi->x = (unsigned)h0 | ((unsigned)h1 << 16);
    hi->y = (unsigned)h2 | ((unsigned)h3 << 16);
    lo->x = (unsigned)f2bf(r0) | ((unsigned)f2bf(r1) << 16);
    lo->y = (unsigned)f2bf(r2) | ((unsigned)f2bf(r3) << 16);
}

// ---------------------------------------------------------------------------
// L1/L2-bypassing (LLC-coherent) memory ops via inline asm. Unlike volatile,
// these BATCH: issue many, then one counted s_waitcnt. Semantics identical to
// the (correct, slow) volatile kernel: loads read the coherent LLC; stores
// write through to LLC (vmcnt completion = at LLC). No L2 dirty lines, so the
// grid barrier needs NO wbl2/inv (the ~10us/sync L2 tag-walk disappears).
__device__ __forceinline__ f4 ldg4_llc(const float* p) {
    f4 v;
    asm volatile("global_load_dwordx4 %0, %1, off sc0 sc1" : "=v"(v) : "v"(p));
    return v;
}
__device__ __forceinline__ float ldg_llc(const float* p) {
    float v;
    asm volatile("global_load_dword %0, %1, off sc0 sc1" : "=v"(v) : "v"(p));
    return v;
}
__device__ __forceinline__ void stg_llc(float* p, float v) {
    asm volatile("global_store_dword %0, %1, off sc0 sc1" :: "v"(p), "v"(v));
}
// wait for all but N outstanding VMEM ops; fence compiler scheduling after
// (rule: consumers of asm-load results must not hoist above the waitcnt).
__device__ __forceinline__ void vm_wait(int n) {
    if (n == 0)       asm volatile("s_waitcnt vmcnt(0)"  ::: "memory");
    else if (n == 16) asm volatile("s_waitcnt vmcnt(16)" ::: "memory");
    __builtin_amdgcn_sched_barrier(0);
}

// ---------------------------------------------------------------------------
// Fence-free grid barrier (32 co-resident blocks). Valid because ALL
// cross-block data uses sc0/sc1 bypass ops: vmcnt(0) means this wave's
// write-through stores are at the LLC; arrivals/spins are agent-scope atomics
// at the LLC; readers bypass L1/L2 so no invalidate is needed.
__device__ __forceinline__ void gsync(unsigned* bar, unsigned target) {
    asm volatile("s_waitcnt vmcnt(0)" ::: "memory");
    __syncthreads();
    if (threadIdx.x == 0) {
        __hip_atomic_fetch_add(bar, 1u, __ATOMIC_RELAXED, __HIP_MEMORY_SCOPE_AGENT);
        while (__hip_atomic_load(bar, __ATOMIC_RELAXED, __HIP_MEMORY_SCOPE_AGENT) < target)
            __builtin_amdgcn_s_sleep(1);
    }
    __syncthreads();
}

// ---------------------------------------------------------------------------
// Kernel 1: Xbf = bf16(X) + per-channel sums (atomic). grid 4096, block 256.
__global__ void prepass_kernel(const float* __restrict__ X, unsigned short* __restrict__ Xbf,
                               float* __restrict__ musum) {
    int b = blockIdx.x;
    int t = threadIdx.x;
    int r = t >> 6;
    int l = t & 63;
    size_t row = (size_t)(4 * b + r);
    const float4* src = (const float4*)(X + (row << 10));
    uint2* dst = (uint2*)(Xbf + (row << 10));
    float s = 0.f;
#pragma unroll
    for (int j = 0; j < 4; ++j) {
        float4 v = src[l + 64 * j];
        uint2 p; p.x = pack2(v.x, v.y); p.y = pack2(v.z, v.w);
        dst[l + 64 * j] = p;
        s += v.x + v.y + v.z + v.w;
    }
    for (int off = 32; off > 0; off >>= 1) s += __shfl_down(s, off);
    if (l == 0) atomicAdd(&musum[(4 * b + r) & 255], s);
}

// ---------------------------------------------------------------------------
// Kernel 2: raw Gram G += X X^T via bf16 MFMA, symmetric (3 unique tiles).
// grid (3 tiles, 128 k-splits), block 512 (8 waves: 2x4 of 64x32).
__global__ __launch_bounds__(512, 3)
void gram_mfma(const unsigned short* __restrict__ Xbf, float* __restrict__ G) {
    int tile = blockIdx.x;               // 0:(0,0) 1:(0,128) 2:(128,128)
    int ci = (tile >> 1) * 128;
    int cj = (tile == 0) ? 0 : 128;
    int ks = blockIdx.y;                 // 0..127, K=512 each
    int t = threadIdx.x, wave = t >> 6, lane = t & 63;
    int wy = wave >> 2, wx = wave & 3;
    int quad = lane >> 4, l16 = lane & 15;

    __shared__ __align__(16) unsigned short As[128 * 72];
    __shared__ __align__(16) unsigned short Bs[128 * 72];
    const unsigned short* Bsrc = (ci == cj) ? As : Bs;

    v4f acc[4][2] = {};
    int n = ks >> 1;
    int hwbase = (ks & 1) * 512;
    const unsigned short* base = Xbf + (((size_t)n * C_DIM) << 10);
    int srow = t >> 2;
    int schunk = t & 3;

    for (int s = 0; s < 8; ++s) {
        int k0 = hwbase + s * 64;
        __syncthreads();
#pragma unroll
        for (int h = 0; h < 2; ++h) {
            int ch = schunk + 4 * h;
            *(uint4*)&As[srow * 72 + ch * 8] =
                *(const uint4*)&base[(((size_t)(ci + srow)) << 10) + k0 + ch * 8];
            if (ci != cj)
                *(uint4*)&Bs[srow * 72 + ch * 8] =
                    *(const uint4*)&base[(((size_t)(cj + srow)) << 10) + k0 + ch * 8];
        }
        __syncthreads();

        short8 af[4][2], bfr[2][2];
#pragma unroll
        for (int mt = 0; mt < 4; ++mt)
#pragma unroll
            for (int kh = 0; kh < 2; ++kh)
                af[mt][kh] = *(const short8*)&As[(64 * wy + 16 * mt + l16) * 72 + kh * 32 + quad * 8];
#pragma unroll
        for (int nt = 0; nt < 2; ++nt)
#pragma unroll
            for (int kh = 0; kh < 2; ++kh)
                bfr[nt][kh] = *(const short8*)&Bsrc[(32 * wx + 16 * nt + l16) * 72 + kh * 32 + quad * 8];
#pragma unroll
        for (int kh = 0; kh < 2; ++kh)
#pragma unroll
            for (int mt = 0; mt < 4; ++mt)
#pragma unroll
                for (int nt = 0; nt < 2; ++nt)
                    acc[mt][nt] = __builtin_amdgcn_mfma_f32_16x16x32_bf16(af[mt][kh], bfr[nt][kh], acc[mt][nt], 0, 0, 0);
    }

#pragma unroll
    for (int mt = 0; mt < 4; ++mt)
#pragma unroll
        for (int nt = 0; nt < 2; ++nt)
#pragma unroll
            for (int r = 0; r < 4; ++r) {
                int row = ci + 64 * wy + 16 * mt + 4 * quad + r;
                int col = cj + 32 * wx + 16 * nt + l16;
                atomicAdd(&G[row * C_DIM + col], acc[mt][nt][r]);
            }
}

// ---------------------------------------------------------------------------
// MFMA 64x64-tile matmul core, K=256, bf16 hi/lo split (~fp32 precision).
// REQUIRES: B symmetric (stages B rows as columns). block 256 (4 waves 2x2).
// Burst bypass loads: 32 x dwordx4 sc0sc1 all in flight; counted waits
// (vmcnt(16) -> convert A while B lands); full-K LDS image; one barrier.
__device__ __forceinline__ void mm_mfma64(const float* __restrict__ A, const float* __restrict__ B,
                                          int ci, int cj, v4f acc[2][2],
                                          unsigned short* Ah, unsigned short* Al,
                                          unsigned short* Bh, unsigned short* Bl) {
    int t = threadIdx.x, wave = t >> 6, lane = t & 63;
    int wy = wave >> 1, wx = wave & 1;
    int quad = lane >> 4, l16 = lane & 15;
    int row = t >> 2, cg_ = (t & 3) * 16;   // row 0..63, col-group base {0,16,32,48}

    f4 va[16], vb[16];
#pragma unroll
    for (int j = 0; j < 4; ++j)
#pragma unroll
        for (int i = 0; i < 4; ++i)
            va[4 * j + i] = ldg4_llc(&A[(ci + row) * C_DIM + 64 * j + cg_ + 4 * i]);
#pragma unroll
    for (int j = 0; j < 4; ++j)
#pragma unroll
        for (int i = 0; i < 4; ++i)
            vb[4 * j + i] = ldg4_llc(&B[(cj + row) * C_DIM + 64 * j + cg_ + 4 * i]);

    vm_wait(16);   // va complete (vb still in flight)
#pragma unroll
    for (int j = 0; j < 16; ++j) {
        uint2 hi, lo;
        int col = 64 * (j >> 2) + cg_ + 4 * (j & 3);
        split4v(va[j], &hi, &lo);
        *(uint2*)&Ah[row * LDK + col] = hi;
        *(uint2*)&Al[row * LDK + col] = lo;
    }
    vm_wait(0);    // vb complete
#pragma unroll
    for (int j = 0; j < 16; ++j) {
        uint2 hi, lo;
        int col = 64 * (j >> 2) + cg_ + 4 * (j & 3);
        split4v(vb[j], &hi, &lo);
        *(uint2*)&Bh[row * LDK + col] = hi;
        *(uint2*)&Bl[row * LDK + col] = lo;
    }
    __syncthreads();

    for (int kb = 0; kb < 256; kb += 64) {
        short8 fah[2][2], fal[2][2], fbh[2][2], fbl[2][2];
#pragma unroll
        for (int mt = 0; mt < 2; ++mt)
#pragma unroll
            for (int kh = 0; kh < 2; ++kh) {
                int off = (32 * wy + 16 * mt + l16) * LDK + kb + kh * 32 + quad * 8;
                fah[mt][kh] = *(const short8*)&Ah[off];
                fal[mt][kh] = *(const short8*)&Al[off];
            }
#pragma unroll
        for (int nt = 0; nt < 2; ++nt)
#pragma unroll
            for (int kh = 0; kh < 2; ++kh) {
                int off = (32 * wx + 16 * nt + l16) * LDK + kb + kh * 32 + quad * 8;
                fbh[nt][kh] = *(const short8*)&Bh[off];
                fbl[nt][kh] = *(const short8*)&Bl[off];
            }
#pragma unroll
        for (int kh = 0; kh < 2; ++kh)
#pragma unroll
            for (int mt = 0; mt < 2; ++mt)
#pragma unroll
                for (int nt = 0; nt < 2; ++nt) {
                    acc[mt][nt] = __builtin_amdgcn_mfma_f32_16x16x32_bf16(fah[mt][kh], fbh[nt][kh], acc[mt][nt], 0, 0, 0);
                    acc[mt][nt] = __builtin_amdgcn_mfma_f32_16x16x32_bf16(fah[mt][kh], fbl[nt][kh], acc[mt][nt], 0, 0, 0);
                    acc[mt][nt] = __builtin_amdgcn_mfma_f32_16x16x32_bf16(fal[mt][kh], fbh[nt][kh], acc[mt][nt], 0, 0, 0);
                }
    }
    // NOTE: LDS reuse across phases is ordered by the caller's gsync (__syncthreads).
}

// ---------------------------------------------------------------------------
// Persistent NS kernel: scal + init + 9 NS iterations + rot, fence-free barrier.
// REGULAR launch, 32 blocks x 256 threads (co-resident on 256 CUs).
// ALL P/Sig/T1/T2 traffic via sc0/sc1 bypass ops -> zero L2 maintenance.
__global__ __launch_bounds__(256, 1)
void ns_persist(const float* __restrict__ G, const float* __restrict__ musum,
                const float* __restrict__ R,
                float* __restrict__ Sig, float* __restrict__ P,
                float* __restrict__ T1, float* __restrict__ T2,
                unsigned short* __restrict__ Mbf, float* __restrict__ moff,
                unsigned* bar) {
    __shared__ __align__(16) unsigned short Ah[64 * LDK];
    __shared__ __align__(16) unsigned short Al[64 * LDK];
    __shared__ __align__(16) unsigned short Bh[64 * LDK];
    __shared__ __align__(16) unsigned short Bl[64 * LDK];
    __shared__ float red[256];
    __shared__ float scal_sh[2];

    int bid = blockIdx.x;
    int t = threadIdx.x;
    int wave = t >> 6, lane = t & 63;
    int wy = wave >> 1, wx = wave & 1, quad = lane >> 4, l16 = lane & 15;
    unsigned tg = 0;

    // ---- Phase 0: trace of Sigma (every block computes identical trr)
    {
        float mu = musum[t] * (1.0f / M_TOTAL);
        float d = G[t * (C_DIM + 1)] * (1.0f / M_TOTAL) - mu * mu + EPS_F;
        red[t] = d;
        __syncthreads();
        for (int off = 128; off > 0; off >>= 1) {
            if (t < off) red[t] += red[t + off];
            __syncthreads();
        }
        if (t == 0) {
            float trr = 1.0f / red[0];
            scal_sh[0] = trr;
            scal_sh[1] = sqrtf(trr);
        }
        __syncthreads();
    }
    float trr = scal_sh[0];
    float s1  = scal_sh[1];

    // ---- Phase 1: Sig = Sigma_N (mirrored symmetric), P = 1.5I - 0.5*Sig.
    // Writes via bypass stores (read by other blocks after gsync).
    {
        int base = bid * 2048 + t;
#pragma unroll
        for (int j = 0; j < 8; ++j) {
            int idx = base + j * 256;
            int r = idx >> 8, c = idx & 255;
            float g = (r >= 128 && c < 128) ? G[c * C_DIM + r] : G[idx];
            float mu_r = musum[r] * (1.0f / M_TOTAL);
            float mu_c = musum[c] * (1.0f / M_TOTAL);
            float sig = (g * (1.0f / M_TOTAL) - mu_r * mu_c + ((r == c) ? EPS_F : 0.f)) * trr;
            stg_llc(&Sig[idx], sig);
            stg_llc(&P[idx], ((r == c) ? 1.5f : 0.f) - 0.5f * sig);
        }
    }
    tg += 32; gsync(bar, tg);

    // ---- Phase 2: 9 Newton-Schulz iterations
    for (int it = 1; it < 10; ++it) {
        {   // A: 32 blocks, two independent matmuls
            int tb = bid & 15;
            int ci = (tb >> 2) * 64, cj = (tb & 3) * 64;
            const float* B = (bid < 16) ? P : Sig;
            float* D = (bid < 16) ? T1 : T2;
            v4f acc[2][2] = {};
            mm_mfma64(P, B, ci, cj, acc, Ah, Al, Bh, Bl);
#pragma unroll
            for (int mt = 0; mt < 2; ++mt)
#pragma unroll
                for (int nt = 0; nt < 2; ++nt)
#pragma unroll
                    for (int r = 0; r < 4; ++r) {
                        int rr = ci + 32 * wy + 16 * mt + 4 * quad + r;
                        int cc = cj + 32 * wx + 16 * nt + l16;
                        stg_llc(&D[rr * C_DIM + cc], acc[mt][nt][r]);
                    }
        }
        tg += 32; gsync(bar, tg);
        if (bid < 16) {  // B: P = 1.5P - 0.5*(T1@T2)   (T2 symmetric: P,Sig commute)
            int ci = (bid >> 2) * 64, cj = (bid & 3) * 64;
            v4f acc[2][2] = {};
            mm_mfma64(T1, T2, ci, cj, acc, Ah, Al, Bh, Bl);
            float pv[2][2][4];
#pragma unroll
            for (int mt = 0; mt < 2; ++mt)
#pragma unroll
                for (int nt = 0; nt < 2; ++nt)
#pragma unroll
                    for (int r = 0; r < 4; ++r) {
                        int rr = ci + 32 * wy + 16 * mt + 4 * quad + r;
                        int cc = cj + 32 * wx + 16 * nt + l16;
                        pv[mt][nt][r] = ldg_llc(&P[rr * C_DIM + cc]);
                    }
            vm_wait(0);
#pragma unroll
            for (int mt = 0; mt < 2; ++mt)
#pragma unroll
                for (int nt = 0; nt < 2; ++nt)
#pragma unroll
                    for (int r = 0; r < 4; ++r) {
                        int rr = ci + 32 * wy + 16 * mt + 4 * quad + r;
                        int cc = cj + 32 * wx + 16 * nt + l16;
                        stg_llc(&P[rr * C_DIM + cc], 1.5f * pv[mt][nt][r] - 0.5f * acc[mt][nt][r]);
                    }
        }
        tg += 32; gsync(bar, tg);
    }

    // ---- Phase 3: rot. M = (R@P)*s1 -> Mbf (bf16) + moff[d] = dot(M[d,:], mu).
    if (bid < 16) {
        int ci = (bid >> 2) * 64, cj = (bid & 3) * 64;
        v4f acc[2][2] = {};
        mm_mfma64(R, P, ci, cj, acc, Ah, Al, Bh, Bl);

        float muc[2];
#pragma unroll
        for (int nt = 0; nt < 2; ++nt)
            muc[nt] = musum[cj + 32 * wx + 16 * nt + l16] * (1.0f / M_TOTAL);
#pragma unroll
        for (int mt = 0; mt < 2; ++mt)
#pragma unroll
            for (int r = 0; r < 4; ++r) {
                int rr = ci + 32 * wy + 16 * mt + 4 * quad + r;
                float s = 0.f;
#pragma unroll
                for (int nt = 0; nt < 2; ++nt) {
                    float val = acc[mt][nt][r] * s1;
                    Mbf[rr * C_DIM + cj + 32 * wx + 16 * nt + l16] = f2bf(val);
                    s += val * muc[nt];
                }
                s += __shfl_xor(s, 1); s += __shfl_xor(s, 2);
                s += __shfl_xor(s, 4); s += __shfl_xor(s, 8);
                if (l16 == 0) atomicAdd(&moff[rr], s);
            }
    }
}

// ---------------------------------------------------------------------------
// Kernel 6: out[n,d,hw] = sum_c Mbf[d,c]*Xbf[n,c,hw] - moff[d]  via MFMA.
// grid: (8 hw-tiles, 2 d-tiles, 64 n), block 256 (4 waves of 64x64).
// Epilogue: LDS transpose -> float4 coalesced stores (full 128B lines).
__global__ void out_mfma(const unsigned short* __restrict__ Xbf,
                         const unsigned short* __restrict__ Mbf,
                         const float* __restrict__ moff, float* __restrict__ out) {
    int hwb = blockIdx.x * 128;
    int db  = blockIdx.y * 128;
    int n   = blockIdx.z;
    int t = threadIdx.x, wave = t >> 6, lane = t & 63;
    int wy = wave >> 1, wx = wave & 1, quad = lane >> 4, l16 = lane & 15;

    __shared__ __align__(16) unsigned short Asm[128 * 40];
    __shared__ __align__(16) unsigned short Bsm[128 * 34];
    __shared__ __align__(16) float Ep[4 * 16 * 68];   // per-wave 16x64 epilogue buffer

    v4f acc[4][4] = {};
    const unsigned short* Xn = Xbf + (((size_t)n * C_DIM) << 10);

    for (int kb = 0; kb < 256; kb += 32) {
        __syncthreads();
#pragma unroll
        for (int i = 0; i < 2; ++i) {
            int a = t + 256 * i;
            int row = a >> 2, c8 = a & 3;
            *(uint4*)(&Asm[row * 40 + 8 * c8]) =
                *(const uint4*)(&Mbf[(db + row) * C_DIM + kb + 8 * c8]);
        }
#pragma unroll
        for (int i = 0; i < 16; ++i) {
            int idx = t + 256 * i;
            int hw = idx & 127, crow = idx >> 7;
            Bsm[hw * 34 + crow] = Xn[(((size_t)(kb + crow)) << 10) + hwb + hw];
        }
        __syncthreads();

        short8 af[4], bfr[4];
#pragma unroll
        for (int mt = 0; mt < 4; ++mt)
            af[mt] = *(const short8*)(&Asm[(64 * wy + 16 * mt + l16) * 40 + 8 * quad]);
#pragma unroll
        for (int nt = 0; nt < 4; ++nt) {
            union { short8 s; unsigned u[4]; } tmp;
            const unsigned short* bp = &Bsm[(64 * wx + 16 * nt + l16) * 34 + 8 * quad];
            tmp.u[0] = *(const unsigned*)(bp + 0);
            tmp.u[1] = *(const unsigned*)(bp + 2);
            tmp.u[2] = *(const unsigned*)(bp + 4);
            tmp.u[3] = *(const unsigned*)(bp + 6);
            bfr[nt] = tmp.s;
        }
#pragma unroll
        for (int mt = 0; mt < 4; ++mt)
#pragma unroll
            for (int nt = 0; nt < 4; ++nt)
                acc[mt][nt] = __builtin_amdgcn_mfma_f32_16x16x32_bf16(af[mt], bfr[nt], acc[mt][nt], 0, 0, 0);
    }

    float* W = &Ep[wave * 16 * 68];
#pragma unroll
    for (int mt = 0; mt < 4; ++mt) {
        // dump this wave's 16x64 tile (row = 4*quad+r, col = 16*nt+l16), moff folded in
#pragma unroll
        for (int r = 0; r < 4; ++r) {
            float off = moff[db + 64 * wy + 16 * mt + 4 * quad + r];
#pragma unroll
            for (int nt = 0; nt < 4; ++nt)
                W[(4 * quad + r) * 68 + 16 * nt + l16] = acc[mt][nt][r] - off;
        }
        __syncthreads();   // orders wave-local LDS ops; uniform across block
        // read back transposed-in-lane: 16 lanes x float4 = 256B contiguous per row
#pragma unroll
        for (int j = 0; j < 4; ++j) {
            int row = 4 * j + quad;
            float4 v = *(const float4*)&W[row * 68 + 4 * l16];
            int d = db + 64 * wy + 16 * mt + row;
            int hw = hwb + 64 * wx + 4 * l16;
            *(float4*)&out[(((size_t)(n * C_DIM + d)) << 10) + hw] = v;
        }
        __syncthreads();
    }
}

// ---------------------------------------------------------------------------
extern "C" void kernel_launch(void* const* d_in, const int* in_sizes, int n_in,
                              void* d_out, int out_size, void* d_ws, size_t ws_size,
                              hipStream_t stream) {
    const float* X = (const float*)d_in[0];        // (64,256,32,32)
    const float* R = (const float*)d_in[1];        // (1,256,256)
    float* out = (float*)d_out;
    float* ws  = (float*)d_ws;

    float* musum = ws;                         // 256
    unsigned* bar = (unsigned*)(ws + 256);     // barrier counter (zeroed by memset)
    float* moff  = ws + 272;                   // 256
    float* G     = ws + 528;                   // 65536 (raw gram, 3 tiles)
    float* Sig   = G + 65536;                  // Sigma_N fp32 (symmetric)
    float* P     = Sig + 65536;
    float* T1    = P + 65536;
    float* T2    = T1 + 65536;
    unsigned short* Mbf = (unsigned short*)(T2 + 65536);   // 65536 ushort
    unsigned short* Xbf = Mbf + 65536;                     // 16M ushort (32 MB)

    hipMemsetAsync(ws, 0, (528 + 65536) * sizeof(float), stream);

    prepass_kernel<<<4096, 256, 0, stream>>>(X, Xbf, musum);
    gram_mfma<<<dim3(3, 128), 512, 0, stream>>>(Xbf, G);

    ns_persist<<<32, 256, 0, stream>>>(G, musum, R, Sig, P, T1, T2, Mbf, moff, bar);

    out_mfma<<<dim3(8, 2, 64), 256, 0, stream>>>(Xbf, Mbf, moff, out);
}

// Round 12
// 346.093 us; speedup vs baseline: 1.7175x; 1.2067x over previous
//
#include <hip/hip_runtime.h>
#include <math.h>

#define C_DIM 256
#define HW_DIM 1024
#define N_DIM 64
#define M_TOTAL (N_DIM * HW_DIM)   // 65536
#define EPS_F 1e-5f

typedef __attribute__((ext_vector_type(8))) short short8;   // 8 bf16 (MFMA A/B frag)
typedef __attribute__((ext_vector_type(4))) float v4f;      // MFMA C/D frag
typedef __attribute__((ext_vector_type(4))) float f4;       // indexable float4

union F4S8 { f4 f; short8 s; };
union S8U  { short8 s; unsigned u[4]; };

// fp32 -> bf16 round-to-nearest-even
__device__ __forceinline__ unsigned short f2bf(float x) {
    unsigned u = __float_as_uint(x);
    u = (u + 0x7FFFu + ((u >> 16) & 1u)) >> 16;
    return (unsigned short)u;
}
__device__ __forceinline__ float bf2f(unsigned short h) {
    return __uint_as_float(((unsigned)h) << 16);
}
__device__ __forceinline__ unsigned pack2(float lo, float hi) {
    return (unsigned)f2bf(lo) | ((unsigned)f2bf(hi) << 16);
}
// split f4 into hi (bf16 RNE) and lo (bf16 of residual)
__device__ __forceinline__ void split4v(f4 v, uint2* hi, uint2* lo) {
    unsigned short h0 = f2bf(v[0]), h1 = f2bf(v[1]), h2 = f2bf(v[2]), h3 = f2bf(v[3]);
    float r0 = v[0] - bf2f(h0), r1 = v[1] - bf2f(h1), r2 = v[2] - bf2f(h2), r3 = v[3] - bf2f(h3);
    hi->x = (unsigned)h0 | ((unsigned)h1 << 16);
    hi->y = (unsigned)h2 | ((unsigned)h3 << 16);
    lo->x = (unsigned)f2bf(r0) | ((unsigned)f2bf(r1) << 16);
    lo->y = (unsigned)f2bf(r2) | ((unsigned)f2bf(r3) << 16);
}

// ---------------------------------------------------------------------------
// L1/L2-bypassing (LLC-coherent) ops. ldg4_llc is the round-9 HW-verified
// form; 16B bf16 frag loads reuse it via union (no new asm constraints).
__device__ __forceinline__ f4 ldg4_llc(const float* p) {
    f4 v;
    asm volatile("global_load_dwordx4 %0, %1, off sc0 sc1" : "=v"(v) : "v"(p));
    return v;
}
__device__ __forceinline__ short8 ldg8b(const unsigned short* p) {
    F4S8 u; u.f = ldg4_llc((const float*)p); return u.s;
}
__device__ __forceinline__ unsigned ldgus_llc(const unsigned short* p) {
    unsigned v;
    asm volatile("global_load_ushort %0, %1, off sc0 sc1" : "=v"(v) : "v"(p));
    return v;
}
__device__ __forceinline__ void stgus_llc(unsigned short* p, unsigned v) {
    asm volatile("global_store_short %0, %1, off sc0 sc1" :: "v"(p), "v"(v));
}
__device__ __forceinline__ void vm_wait0() {
    asm volatile("s_waitcnt vmcnt(0)" ::: "memory");
    __builtin_amdgcn_sched_barrier(0);   // keep consumers below the wait
}

// ---------------------------------------------------------------------------
// Fence-free grid barrier (round-9 HW-verified). All cross-block data uses
// sc0/sc1 bypass ops: vmcnt(0) => this wave's stores are at the coherent LLC.
__device__ __forceinline__ void gsync(unsigned* bar, unsigned target) {
    asm volatile("s_waitcnt vmcnt(0)" ::: "memory");
    __syncthreads();
    if (threadIdx.x == 0) {
        __hip_atomic_fetch_add(bar, 1u, __ATOMIC_RELAXED, __HIP_MEMORY_SCOPE_AGENT);
        while (__hip_atomic_load(bar, __ATOMIC_RELAXED, __HIP_MEMORY_SCOPE_AGENT) < target)
            __builtin_amdgcn_s_sleep(1);
    }
    __syncthreads();
}

// ---------------------------------------------------------------------------
// Kernel 1: Xbf = bf16(X) + per-channel sums (atomic). grid 4096, block 256.
__global__ void prepass_kernel(const float* __restrict__ X, unsigned short* __restrict__ Xbf,
                               float* __restrict__ musum) {
    int b = blockIdx.x;
    int t = threadIdx.x;
    int r = t >> 6;
    int l = t & 63;
    size_t row = (size_t)(4 * b + r);
    const float4* src = (const float4*)(X + (row << 10));
    uint2* dst = (uint2*)(Xbf + (row << 10));
    float s = 0.f;
#pragma unroll
    for (int j = 0; j < 4; ++j) {
        float4 v = src[l + 64 * j];
        uint2 p; p.x = pack2(v.x, v.y); p.y = pack2(v.z, v.w);
        dst[l + 64 * j] = p;
        s += v.x + v.y + v.z + v.w;
    }
    for (int off = 32; off > 0; off >>= 1) s += __shfl_down(s, off);
    if (l == 0) atomicAdd(&musum[(4 * b + r) & 255], s);
}

// ---------------------------------------------------------------------------
// Kernel 2: raw Gram G += X X^T via bf16 MFMA, symmetric (3 unique tiles).
__global__ __launch_bounds__(512, 3)
void gram_mfma(const unsigned short* __restrict__ Xbf, float* __restrict__ G) {
    int tile = blockIdx.x;               // 0:(0,0) 1:(0,128) 2:(128,128)
    int ci = (tile >> 1) * 128;
    int cj = (tile == 0) ? 0 : 128;
    int ks = blockIdx.y;                 // 0..127, K=512 each
    int t = threadIdx.x, wave = t >> 6, lane = t & 63;
    int wy = wave >> 2, wx = wave & 3;
    int quad = lane >> 4, l16 = lane & 15;

    __shared__ __align__(16) unsigned short As[128 * 72];
    __shared__ __align__(16) unsigned short Bs[128 * 72];
    const unsigned short* Bsrc = (ci == cj) ? As : Bs;

    v4f acc[4][2] = {};
    int n = ks >> 1;
    int hwbase = (ks & 1) * 512;
    const unsigned short* base = Xbf + (((size_t)n * C_DIM) << 10);
    int srow = t >> 2;
    int schunk = t & 3;

    for (int s = 0; s < 8; ++s) {
        int k0 = hwbase + s * 64;
        __syncthreads();
#pragma unroll
        for (int h = 0; h < 2; ++h) {
            int ch = schunk + 4 * h;
            *(uint4*)&As[srow * 72 + ch * 8] =
                *(const uint4*)&base[(((size_t)(ci + srow)) << 10) + k0 + ch * 8];
            if (ci != cj)
                *(uint4*)&Bs[srow * 72 + ch * 8] =
                    *(const uint4*)&base[(((size_t)(cj + srow)) << 10) + k0 + ch * 8];
        }
        __syncthreads();

        short8 af[4][2], bfr[2][2];
#pragma unroll
        for (int mt = 0; mt < 4; ++mt)
#pragma unroll
            for (int kh = 0; kh < 2; ++kh)
                af[mt][kh] = *(const short8*)&As[(64 * wy + 16 * mt + l16) * 72 + kh * 32 + quad * 8];
#pragma unroll
        for (int nt = 0; nt < 2; ++nt)
#pragma unroll
            for (int kh = 0; kh < 2; ++kh)
                bfr[nt][kh] = *(const short8*)&Bsrc[(32 * wx + 16 * nt + l16) * 72 + kh * 32 + quad * 8];
#pragma unroll
        for (int kh = 0; kh < 2; ++kh)
#pragma unroll
            for (int mt = 0; mt < 4; ++mt)
#pragma unroll
                for (int nt = 0; nt < 2; ++nt)
                    acc[mt][nt] = __builtin_amdgcn_mfma_f32_16x16x32_bf16(af[mt][kh], bfr[nt][kh], acc[mt][nt], 0, 0, 0);
    }

#pragma unroll
    for (int mt = 0; mt < 4; ++mt)
#pragma unroll
        for (int nt = 0; nt < 2; ++nt)
#pragma unroll
            for (int r = 0; r < 4; ++r) {
                int row = ci + 64 * wy + 16 * mt + 4 * quad + r;
                int col = cj + 32 * wx + 16 * nt + l16;
                atomicAdd(&G[row * C_DIM + col], acc[mt][nt][r]);
            }
}

// ---------------------------------------------------------------------------
// Persistent NS kernel, FULL-DEVICE: 256 blocks x 256 threads (1 block/CU).
// All matrices stored as pre-split bf16 hi/lo; MFMA fragments load directly
// from global (16B each); K split across the 4 waves; 8KB LDS K-reduction.
// Phase A: 256 jobs (T1=P@P tiles 32x16 for bid<128; T2=P@Sig for bid>=128).
// Phase B: 256 jobs (16x16 tiles of P' = 1.5P - 0.5*T1@T2).
__global__ __launch_bounds__(256, 1)
void ns_persist(const float* __restrict__ G, const float* __restrict__ musum,
                const float* __restrict__ R,
                unsigned short* Ph, unsigned short* Pl,
                unsigned short* Sh, unsigned short* Sl,
                unsigned short* T1h, unsigned short* T1l,
                unsigned short* T2h, unsigned short* T2l,
                unsigned short* __restrict__ Mbf, float* __restrict__ moff,
                unsigned* bar) {
    __shared__ float part[4 * 512];    // 8 KB wave-partial buffer
    __shared__ float red[256];
    __shared__ float scal_sh[2];

    int bid = blockIdx.x;
    int t = threadIdx.x;
    int wv = t >> 6, lane = t & 63;
    int quad = lane >> 4, l16 = lane & 15;
    int kb = wv * 64;                  // this wave's K-chunk
    unsigned tg = 0;

    // ---- Phase 0: trace of Sigma (every block computes identical trr)
    {
        float mu = musum[t] * (1.0f / M_TOTAL);
        float d = G[t * (C_DIM + 1)] * (1.0f / M_TOTAL) - mu * mu + EPS_F;
        red[t] = d;
        __syncthreads();
        for (int off = 128; off > 0; off >>= 1) {
            if (t < off) red[t] += red[t + off];
            __syncthreads();
        }
        if (t == 0) {
            float trr = 1.0f / red[0];
            scal_sh[0] = trr;
            scal_sh[1] = sqrtf(trr);
        }
        __syncthreads();
    }
    float trr = scal_sh[0];
    float s1  = scal_sh[1];

    // ---- Phase 1: Sig -> Sh/Sl; P = 1.5I - 0.5*Sig -> Ph/Pl. 1 elem/thread.
    {
        int idx = bid * 256 + t;
        int r = idx >> 8, c = idx & 255;
        float g = (r >= 128 && c < 128) ? G[c * C_DIM + r] : G[idx];
        float mu_r = musum[r] * (1.0f / M_TOTAL);
        float mu_c = musum[c] * (1.0f / M_TOTAL);
        float sig = (g * (1.0f / M_TOTAL) - mu_r * mu_c + ((r == c) ? EPS_F : 0.f)) * trr;
        float p0  = ((r == c) ? 1.5f : 0.f) - 0.5f * sig;
        unsigned short sh_ = f2bf(sig);
        unsigned short sl_ = f2bf(sig - bf2f(sh_));
        unsigned short ph_ = f2bf(p0);
        unsigned short pl_ = f2bf(p0 - bf2f(ph_));
        stgus_llc(&Sh[idx], sh_); stgus_llc(&Sl[idx], sl_);
        stgus_llc(&Ph[idx], ph_); stgus_llc(&Pl[idx], pl_);
    }
    tg += 256; gsync(bar, tg);

    // ---- Phase 2: 9 Newton-Schulz iterations
    for (int it = 1; it < 10; ++it) {
        {   // -------- Phase A: 32x16 tile per block, wave K-split ----------
            bool isT2 = (bid >= 128);
            int b = bid & 127;
            int ci = (b >> 4) * 32, cj = (b & 15) * 16;
            const unsigned short* Bh_ = isT2 ? Sh : Ph;
            const unsigned short* Bl_ = isT2 ? Sl : Pl;
            unsigned short* Dh = isT2 ? T2h : T1h;
            unsigned short* Dl = isT2 ? T2l : T1l;

            short8 ah[2][2], al[2][2], bh[2], bl[2];
#pragma unroll
            for (int mt = 0; mt < 2; ++mt)
#pragma unroll
                for (int ks = 0; ks < 2; ++ks) {
                    int off = (ci + 16 * mt + l16) * C_DIM + kb + 32 * ks + 8 * quad;
                    ah[mt][ks] = ldg8b(&Ph[off]);
                    al[mt][ks] = ldg8b(&Pl[off]);
                }
#pragma unroll
            for (int ks = 0; ks < 2; ++ks) {
                int off = (cj + l16) * C_DIM + kb + 32 * ks + 8 * quad;
                bh[ks] = ldg8b(&Bh_[off]);
                bl[ks] = ldg8b(&Bl_[off]);
            }
            vm_wait0();
            v4f acc[2] = {};
#pragma unroll
            for (int ks = 0; ks < 2; ++ks)
#pragma unroll
                for (int mt = 0; mt < 2; ++mt) {
                    acc[mt] = __builtin_amdgcn_mfma_f32_16x16x32_bf16(ah[mt][ks], bh[ks], acc[mt], 0, 0, 0);
                    acc[mt] = __builtin_amdgcn_mfma_f32_16x16x32_bf16(ah[mt][ks], bl[ks], acc[mt], 0, 0, 0);
                    acc[mt] = __builtin_amdgcn_mfma_f32_16x16x32_bf16(al[mt][ks], bh[ks], acc[mt], 0, 0, 0);
                }
#pragma unroll
            for (int mt = 0; mt < 2; ++mt)
#pragma unroll
                for (int r = 0; r < 4; ++r)
                    part[wv * 512 + (16 * mt + 4 * quad + r) * 16 + l16] = acc[mt][r];
            __syncthreads();
#pragma unroll
            for (int e = 0; e < 512; e += 256) {
                int ee = e + t;
                float v = part[ee] + part[512 + ee] + part[1024 + ee] + part[1536 + ee];
                int row = ee >> 4, col = ee & 15;
                unsigned short h = f2bf(v);
                unsigned short lo2 = f2bf(v - bf2f(h));
                int gidx = (ci + row) * C_DIM + cj + col;
                stgus_llc(&Dh[gidx], h);
                stgus_llc(&Dl[gidx], lo2);
            }
        }
        tg += 256; gsync(bar, tg);
        {   // -------- Phase B: 16x16 tile per block, P' = 1.5P - 0.5*T1@T2 --
            int ci = (bid >> 4) * 16, cj = (bid & 15) * 16;
            short8 ah[2], al[2], bh[2], bl[2];
#pragma unroll
            for (int ks = 0; ks < 2; ++ks) {
                int offa = (ci + l16) * C_DIM + kb + 32 * ks + 8 * quad;
                int offb = (cj + l16) * C_DIM + kb + 32 * ks + 8 * quad;
                ah[ks] = ldg8b(&T1h[offa]);
                al[ks] = ldg8b(&T1l[offa]);
                bh[ks] = ldg8b(&T2h[offb]);
                bl[ks] = ldg8b(&T2l[offb]);
            }
            vm_wait0();
            v4f acc = {};
#pragma unroll
            for (int ks = 0; ks < 2; ++ks) {
                acc = __builtin_amdgcn_mfma_f32_16x16x32_bf16(ah[ks], bh[ks], acc, 0, 0, 0);
                acc = __builtin_amdgcn_mfma_f32_16x16x32_bf16(ah[ks], bl[ks], acc, 0, 0, 0);
                acc = __builtin_amdgcn_mfma_f32_16x16x32_bf16(al[ks], bh[ks], acc, 0, 0, 0);
            }
#pragma unroll
            for (int r = 0; r < 4; ++r)
                part[wv * 256 + (4 * quad + r) * 16 + l16] = acc[r];
            __syncthreads();
            {
                float u = part[t] + part[256 + t] + part[512 + t] + part[768 + t];
                int row = t >> 4, col = t & 15;
                int gidx = (ci + row) * C_DIM + cj + col;
                unsigned hu = ldgus_llc(&Ph[gidx]);
                unsigned lu = ldgus_llc(&Pl[gidx]);
                vm_wait0();
                float p = bf2f((unsigned short)hu) + bf2f((unsigned short)lu);
                float v = 1.5f * p - 0.5f * u;
                unsigned short h = f2bf(v);
                unsigned short lo2 = f2bf(v - bf2f(h));
                stgus_llc(&Ph[gidx], h);
                stgus_llc(&Pl[gidx], lo2);
            }
        }
        tg += 256; gsync(bar, tg);
    }

    // ---- Phase 3: rot. M = (R@P)*s1 -> Mbf + moff. 16x16 tile per block.
    {
        int ci = (bid >> 4) * 16, cj = (bid & 15) * 16;
        short8 rh[2], rl[2], bh[2], bl[2];
#pragma unroll
        for (int ks = 0; ks < 2; ++ks) {
            const float* rp = &R[(ci + l16) * C_DIM + kb + 32 * ks + 8 * quad];
            f4 a0 = *(const f4*)rp;
            f4 a1 = *(const f4*)(rp + 4);
            uint2 h0, l0, h1, l1;
            split4v(a0, &h0, &l0);
            split4v(a1, &h1, &l1);
            S8U sh_; sh_.u[0] = h0.x; sh_.u[1] = h0.y; sh_.u[2] = h1.x; sh_.u[3] = h1.y;
            S8U sl_; sl_.u[0] = l0.x; sl_.u[1] = l0.y; sl_.u[2] = l1.x; sl_.u[3] = l1.y;
            rh[ks] = sh_.s;
            rl[ks] = sl_.s;
            int offb = (cj + l16) * C_DIM + kb + 32 * ks + 8 * quad;
            bh[ks] = ldg8b(&Ph[offb]);
            bl[ks] = ldg8b(&Pl[offb]);
        }
        vm_wait0();
        v4f acc = {};
#pragma unroll
        for (int ks = 0; ks < 2; ++ks) {
            acc = __builtin_amdgcn_mfma_f32_16x16x32_bf16(rh[ks], bh[ks], acc, 0, 0, 0);
            acc = __builtin_amdgcn_mfma_f32_16x16x32_bf16(rh[ks], bl[ks], acc, 0, 0, 0);
            acc = __builtin_amdgcn_mfma_f32_16x16x32_bf16(rl[ks], bh[ks], acc, 0, 0, 0);
        }
#pragma unroll
        for (int r = 0; r < 4; ++r)
            part[wv * 256 + (4 * quad + r) * 16 + l16] = acc[r];
        __syncthreads();
        float u = part[t] + part[256 + t] + part[512 + t] + part[768 + t];
        int row = t >> 4, col = t & 15;
        float val = u * s1;
        Mbf[(ci + row) * C_DIM + cj + col] = f2bf(val);        // plain store: next-kernel boundary flushes
        float contrib = val * (musum[cj + col] * (1.0f / M_TOTAL));
        __syncthreads();
        part[t] = contrib;
        __syncthreads();
        if ((t & 15) == 0) {
            float s = 0.f;
#pragma unroll
            for (int i = 0; i < 16; ++i) s += part[t + i];
            atomicAdd(&moff[ci + (t >> 4)], s);
        }
    }
}

// ---------------------------------------------------------------------------
// Kernel 6: out[n,d,hw] = sum_c Mbf[d,c]*Xbf[n,c,hw] - moff[d]  via MFMA.
__global__ void out_mfma(const unsigned short* __restrict__ Xbf,
                         const unsigned short* __restrict__ Mbf,
                         const float* __restrict__ moff, float* __restrict__ out) {
    int hwb = blockIdx.x * 128;
    int db  = blockIdx.y * 128;
    int n   = blockIdx.z;
    int t = threadIdx.x, wave = t >> 6, lane = t & 63;
    int wy = wave >> 1, wx = wave & 1, quad = lane >> 4, l16 = lane & 15;

    __shared__ __align__(16) unsigned short Asm[128 * 40];
    __shared__ __align__(16) unsigned short Bsm[128 * 34];
    __shared__ __align__(16) float Ep[4 * 16 * 68];   // per-wave 16x64 epilogue buffer

    v4f acc[4][4] = {};
    const unsigned short* Xn = Xbf + (((size_t)n * C_DIM) << 10);

    for (int kb = 0; kb < 256; kb += 32) {
        __syncthreads();
#pragma unroll
        for (int i = 0; i < 2; ++i) {
            int a = t + 256 * i;
            int row = a >> 2, c8 = a & 3;
            *(uint4*)(&Asm[row * 40 + 8 * c8]) =
                *(const uint4*)(&Mbf[(db + row) * C_DIM + kb + 8 * c8]);
        }
#pragma unroll
        for (int i = 0; i < 16; ++i) {
            int idx = t + 256 * i;
            int hw = idx & 127, crow = idx >> 7;
            Bsm[hw * 34 + crow] = Xn[(((size_t)(kb + crow)) << 10) + hwb + hw];
        }
        __syncthreads();

        short8 af[4], bfr[4];
#pragma unroll
        for (int mt = 0; mt < 4; ++mt)
            af[mt] = *(const short8*)(&Asm[(64 * wy + 16 * mt + l16) * 40 + 8 * quad]);
#pragma unroll
        for (int nt = 0; nt < 4; ++nt) {
            union { short8 s; unsigned u[4]; } tmp;
            const unsigned short* bp = &Bsm[(64 * wx + 16 * nt + l16) * 34 + 8 * quad];
            tmp.u[0] = *(const unsigned*)(bp + 0);
            tmp.u[1] = *(const unsigned*)(bp + 2);
            tmp.u[2] = *(const unsigned*)(bp + 4);
            tmp.u[3] = *(const unsigned*)(bp + 6);
            bfr[nt] = tmp.s;
        }
#pragma unroll
        for (int mt = 0; mt < 4; ++mt)
#pragma unroll
            for (int nt = 0; nt < 4; ++nt)
                acc[mt][nt] = __builtin_amdgcn_mfma_f32_16x16x32_bf16(af[mt], bfr[nt], acc[mt][nt], 0, 0, 0);
    }

    float* W = &Ep[wave * 16 * 68];
#pragma unroll
    for (int mt = 0; mt < 4; ++mt) {
#pragma unroll
        for (int r = 0; r < 4; ++r) {
            float off = moff[db + 64 * wy + 16 * mt + 4 * quad + r];
#pragma unroll
            for (int nt = 0; nt < 4; ++nt)
                W[(4 * quad + r) * 68 + 16 * nt + l16] = acc[mt][nt][r] - off;
        }
        __syncthreads();
#pragma unroll
        for (int j = 0; j < 4; ++j) {
            int row = 4 * j + quad;
            float4 v = *(const float4*)&W[row * 68 + 4 * l16];
            int d = db + 64 * wy + 16 * mt + row;
            int hw = hwb + 64 * wx + 4 * l16;
            *(float4*)&out[(((size_t)(n * C_DIM + d)) << 10) + hw] = v;
        }
        __syncthreads();
    }
}

// ---------------------------------------------------------------------------
extern "C" void kernel_launch(void* const* d_in, const int* in_sizes, int n_in,
                              void* d_out, int out_size, void* d_ws, size_t ws_size,
                              hipStream_t stream) {
    const float* X = (const float*)d_in[0];        // (64,256,32,32)
    const float* R = (const float*)d_in[1];        // (1,256,256)
    float* out = (float*)d_out;
    float* ws  = (float*)d_ws;

    float* musum = ws;                         // 256
    unsigned* bar = (unsigned*)(ws + 256);     // barrier counter (zeroed by memset)
    float* moff  = ws + 272;                   // 256
    float* G     = ws + 528;                   // 65536 fp32 (raw gram, 3 tiles)
    unsigned short* Ph  = (unsigned short*)(G + 65536);   // 9 x 65536 ushort arrays
    unsigned short* Pl  = Ph  + 65536;
    unsigned short* Sh  = Pl  + 65536;
    unsigned short* Sl  = Sh  + 65536;
    unsigned short* T1h = Sl  + 65536;
    unsigned short* T1l = T1h + 65536;
    unsigned short* T2h = T1l + 65536;
    unsigned short* T2l = T2h + 65536;
    unsigned short* Mbf = T2l + 65536;
    unsigned short* Xbf = Mbf + 65536;                    // 16M ushort (32 MB)

    hipMemsetAsync(ws, 0, (528 + 65536) * sizeof(float), stream);

    prepass_kernel<<<4096, 256, 0, stream>>>(X, Xbf, musum);
    gram_mfma<<<dim3(3, 128), 512, 0, stream>>>(Xbf, G);

    ns_persist<<<256, 256, 0, stream>>>(G, musum, R, Ph, Pl, Sh, Sl,
                                        T1h, T1l, T2h, T2l, Mbf, moff, bar);

    out_mfma<<<dim3(8, 2, 64), 256, 0, stream>>>(Xbf, Mbf, moff, out);
}

// Round 13
// 281.646 us; speedup vs baseline: 2.1105x; 1.2288x over previous
//
#include <hip/hip_runtime.h>
#include <math.h>

#define C_DIM 256
#define HW_DIM 1024
#define N_DIM 64
#define M_TOTAL (N_DIM * HW_DIM)   // 65536
#define EPS_F 1e-5f

typedef __attribute__((ext_vector_type(8))) short short8;   // 8 bf16 (MFMA A/B frag)
typedef __attribute__((ext_vector_type(4))) float v4f;      // MFMA C/D frag
typedef __attribute__((ext_vector_type(4))) float f4;       // indexable float4

union F4S8 { f4 f; short8 s; };
union S8U  { short8 s; unsigned u[4]; };

// fp32 -> bf16 round-to-nearest-even
__device__ __forceinline__ unsigned short f2bf(float x) {
    unsigned u = __float_as_uint(x);
    u = (u + 0x7FFFu + ((u >> 16) & 1u)) >> 16;
    return (unsigned short)u;
}
__device__ __forceinline__ float bf2f(unsigned short h) {
    return __uint_as_float(((unsigned)h) << 16);
}
__device__ __forceinline__ unsigned pack2(float lo, float hi) {
    return (unsigned)f2bf(lo) | ((unsigned)f2bf(hi) << 16);
}
// split f4 into hi (bf16 RNE) and lo (bf16 of residual)
__device__ __forceinline__ void split4v(f4 v, uint2* hi, uint2* lo) {
    unsigned short h0 = f2bf(v[0]), h1 = f2bf(v[1]), h2 = f2bf(v[2]), h3 = f2bf(v[3]);
    float r0 = v[0] - bf2f(h0), r1 = v[1] - bf2f(h1), r2 = v[2] - bf2f(h2), r3 = v[3] - bf2f(h3);
    hi->x = (unsigned)h0 | ((unsigned)h1 << 16);
    hi->y = (unsigned)h2 | ((unsigned)h3 << 16);
    lo->x = (unsigned)f2bf(r0) | ((unsigned)f2bf(r1) << 16);
    lo->y = (unsigned)f2bf(r2) | ((unsigned)f2bf(r3) << 16);
}

// ---------------------------------------------------------------------------
// L1/L2-bypassing (LLC-coherent) ops. ldg4_llc is the round-9 HW-verified
// form; 16B bf16 frag loads reuse it via union (no new asm constraints).
__device__ __forceinline__ f4 ldg4_llc(const float* p) {
    f4 v;
    asm volatile("global_load_dwordx4 %0, %1, off sc0 sc1" : "=v"(v) : "v"(p));
    return v;
}
__device__ __forceinline__ short8 ldg8b(const unsigned short* p) {
    F4S8 u; u.f = ldg4_llc((const float*)p); return u.s;
}
__device__ __forceinline__ unsigned ldgus_llc(const unsigned short* p) {
    unsigned v;
    asm volatile("global_load_ushort %0, %1, off sc0 sc1" : "=v"(v) : "v"(p));
    return v;
}
__device__ __forceinline__ void stgus_llc(unsigned short* p, unsigned v) {
    asm volatile("global_store_short %0, %1, off sc0 sc1" :: "v"(p), "v"(v));
}
__device__ __forceinline__ void vm_wait0() {
    asm volatile("s_waitcnt vmcnt(0)" ::: "memory");
    __builtin_amdgcn_sched_barrier(0);   // keep consumers below the wait
}

// ---------------------------------------------------------------------------
// Two-level fence-free grid barrier (256 blocks, 16 leaves x 16 blocks).
// Each leaf counter sits on its own 128B line -> same-line atomic RMW chains
// shrink from 256 to 16 (leaf) + 16 (root). Memory semantics = round-9
// verified: all cross-block data uses sc0/sc1 bypass, so vmcnt(0) before
// arrival means this block's stores are visible at the coherent LLC.
// p = 1-based phase number; leaf target = 16p, root target = 16p.
__device__ __forceinline__ void gsync(unsigned* bar, int bid, unsigned p) {
    asm volatile("s_waitcnt vmcnt(0)" ::: "memory");
    __syncthreads();
    if (threadIdx.x == 0) {
        unsigned* leaf = bar + ((unsigned)(bid & 15)) * 32;   // 128B apart
        unsigned* root = bar + 16 * 32;
        unsigned prev = __hip_atomic_fetch_add(leaf, 1u, __ATOMIC_RELAXED, __HIP_MEMORY_SCOPE_AGENT);
        if (prev == 16u * p - 1u)
            __hip_atomic_fetch_add(root, 1u, __ATOMIC_RELAXED, __HIP_MEMORY_SCOPE_AGENT);
        while (__hip_atomic_load(root, __ATOMIC_RELAXED, __HIP_MEMORY_SCOPE_AGENT) < 16u * p)
            __builtin_amdgcn_s_sleep(1);
    }
    __syncthreads();
}

// ---------------------------------------------------------------------------
// Kernel 1: Xbf = bf16(X) + per-channel sums (atomic). grid 4096, block 256.
__global__ void prepass_kernel(const float* __restrict__ X, unsigned short* __restrict__ Xbf,
                               float* __restrict__ musum) {
    int b = blockIdx.x;
    int t = threadIdx.x;
    int r = t >> 6;
    int l = t & 63;
    size_t row = (size_t)(4 * b + r);
    const float4* src = (const float4*)(X + (row << 10));
    uint2* dst = (uint2*)(Xbf + (row << 10));
    float s = 0.f;
#pragma unroll
    for (int j = 0; j < 4; ++j) {
        float4 v = src[l + 64 * j];
        uint2 p; p.x = pack2(v.x, v.y); p.y = pack2(v.z, v.w);
        dst[l + 64 * j] = p;
        s += v.x + v.y + v.z + v.w;
    }
    for (int off = 32; off > 0; off >>= 1) s += __shfl_down(s, off);
    if (l == 0) atomicAdd(&musum[(4 * b + r) & 255], s);
}

// ---------------------------------------------------------------------------
// Kernel 2: raw Gram G += X X^T via bf16 MFMA, symmetric (3 unique tiles).
__global__ __launch_bounds__(512, 3)
void gram_mfma(const unsigned short* __restrict__ Xbf, float* __restrict__ G) {
    int tile = blockIdx.x;               // 0:(0,0) 1:(0,128) 2:(128,128)
    int ci = (tile >> 1) * 128;
    int cj = (tile == 0) ? 0 : 128;
    int ks = blockIdx.y;                 // 0..127, K=512 each
    int t = threadIdx.x, wave = t >> 6, lane = t & 63;
    int wy = wave >> 2, wx = wave & 3;
    int quad = lane >> 4, l16 = lane & 15;

    __shared__ __align__(16) unsigned short As[128 * 72];
    __shared__ __align__(16) unsigned short Bs[128 * 72];
    const unsigned short* Bsrc = (ci == cj) ? As : Bs;

    v4f acc[4][2] = {};
    int n = ks >> 1;
    int hwbase = (ks & 1) * 512;
    const unsigned short* base = Xbf + (((size_t)n * C_DIM) << 10);
    int srow = t >> 2;
    int schunk = t & 3;

    for (int s = 0; s < 8; ++s) {
        int k0 = hwbase + s * 64;
        __syncthreads();
#pragma unroll
        for (int h = 0; h < 2; ++h) {
            int ch = schunk + 4 * h;
            *(uint4*)&As[srow * 72 + ch * 8] =
                *(const uint4*)&base[(((size_t)(ci + srow)) << 10) + k0 + ch * 8];
            if (ci != cj)
                *(uint4*)&Bs[srow * 72 + ch * 8] =
                    *(const uint4*)&base[(((size_t)(cj + srow)) << 10) + k0 + ch * 8];
        }
        __syncthreads();

        short8 af[4][2], bfr[2][2];
#pragma unroll
        for (int mt = 0; mt < 4; ++mt)
#pragma unroll
            for (int kh = 0; kh < 2; ++kh)
                af[mt][kh] = *(const short8*)&As[(64 * wy + 16 * mt + l16) * 72 + kh * 32 + quad * 8];
#pragma unroll
        for (int nt = 0; nt < 2; ++nt)
#pragma unroll
            for (int kh = 0; kh < 2; ++kh)
                bfr[nt][kh] = *(const short8*)&Bsrc[(32 * wx + 16 * nt + l16) * 72 + kh * 32 + quad * 8];
#pragma unroll
        for (int kh = 0; kh < 2; ++kh)
#pragma unroll
            for (int mt = 0; mt < 4; ++mt)
#pragma unroll
                for (int nt = 0; nt < 2; ++nt)
                    acc[mt][nt] = __builtin_amdgcn_mfma_f32_16x16x32_bf16(af[mt][kh], bfr[nt][kh], acc[mt][nt], 0, 0, 0);
    }

#pragma unroll
    for (int mt = 0; mt < 4; ++mt)
#pragma unroll
        for (int nt = 0; nt < 2; ++nt)
#pragma unroll
            for (int r = 0; r < 4; ++r) {
                int row = ci + 64 * wy + 16 * mt + 4 * quad + r;
                int col = cj + 32 * wx + 16 * nt + l16;
                atomicAdd(&G[row * C_DIM + col], acc[mt][nt][r]);
            }
}

// ---------------------------------------------------------------------------
// Persistent NS kernel, FULL-DEVICE: 256 blocks x 256 threads (1 block/CU).
// Matrices stored pre-split bf16 hi/lo; MFMA fragments load directly from
// global; K split across 4 waves; 8KB LDS K-reduction; tree barrier.
__global__ __launch_bounds__(256, 1)
void ns_persist(const float* __restrict__ G, const float* __restrict__ musum,
                const float* __restrict__ R,
                unsigned short* Ph, unsigned short* Pl,
                unsigned short* Sh, unsigned short* Sl,
                unsigned short* T1h, unsigned short* T1l,
                unsigned short* T2h, unsigned short* T2l,
                unsigned short* __restrict__ Mbf, float* __restrict__ moff,
                unsigned* bar) {
    __shared__ float part[4 * 512];    // 8 KB wave-partial buffer
    __shared__ float red[256];
    __shared__ float scal_sh[2];

    int bid = blockIdx.x;
    int t = threadIdx.x;
    int wv = t >> 6, lane = t & 63;
    int quad = lane >> 4, l16 = lane & 15;
    int kb = wv * 64;                  // this wave's K-chunk
    unsigned ph = 0;                   // phase counter for tree barrier

    // ---- Phase 0: trace of Sigma (every block computes identical trr)
    {
        float mu = musum[t] * (1.0f / M_TOTAL);
        float d = G[t * (C_DIM + 1)] * (1.0f / M_TOTAL) - mu * mu + EPS_F;
        red[t] = d;
        __syncthreads();
        for (int off = 128; off > 0; off >>= 1) {
            if (t < off) red[t] += red[t + off];
            __syncthreads();
        }
        if (t == 0) {
            float trr = 1.0f / red[0];
            scal_sh[0] = trr;
            scal_sh[1] = sqrtf(trr);
        }
        __syncthreads();
    }
    float trr = scal_sh[0];
    float s1  = scal_sh[1];

    // ---- Phase 1: Sig -> Sh/Sl; P = 1.5I - 0.5*Sig -> Ph/Pl. 1 elem/thread.
    {
        int idx = bid * 256 + t;
        int r = idx >> 8, c = idx & 255;
        float g = (r >= 128 && c < 128) ? G[c * C_DIM + r] : G[idx];
        float mu_r = musum[r] * (1.0f / M_TOTAL);
        float mu_c = musum[c] * (1.0f / M_TOTAL);
        float sig = (g * (1.0f / M_TOTAL) - mu_r * mu_c + ((r == c) ? EPS_F : 0.f)) * trr;
        float p0  = ((r == c) ? 1.5f : 0.f) - 0.5f * sig;
        unsigned short sh_ = f2bf(sig);
        unsigned short sl_ = f2bf(sig - bf2f(sh_));
        unsigned short ph_ = f2bf(p0);
        unsigned short pl_ = f2bf(p0 - bf2f(ph_));
        stgus_llc(&Sh[idx], sh_); stgus_llc(&Sl[idx], sl_);
        stgus_llc(&Ph[idx], ph_); stgus_llc(&Pl[idx], pl_);
    }
    ++ph; gsync(bar, bid, ph);

    // ---- Phase 2: 9 Newton-Schulz iterations
    for (int it = 1; it < 10; ++it) {
        {   // -------- Phase A: 32x16 tile per block, wave K-split ----------
            bool isT2 = (bid >= 128);
            int b = bid & 127;
            int ci = (b >> 4) * 32, cj = (b & 15) * 16;
            const unsigned short* Bh_ = isT2 ? Sh : Ph;
            const unsigned short* Bl_ = isT2 ? Sl : Pl;
            unsigned short* Dh = isT2 ? T2h : T1h;
            unsigned short* Dl = isT2 ? T2l : T1l;

            short8 ah[2][2], al[2][2], bh[2], bl[2];
#pragma unroll
            for (int mt = 0; mt < 2; ++mt)
#pragma unroll
                for (int ks = 0; ks < 2; ++ks) {
                    int off = (ci + 16 * mt + l16) * C_DIM + kb + 32 * ks + 8 * quad;
                    ah[mt][ks] = ldg8b(&Ph[off]);
                    al[mt][ks] = ldg8b(&Pl[off]);
                }
#pragma unroll
            for (int ks = 0; ks < 2; ++ks) {
                int off = (cj + l16) * C_DIM + kb + 32 * ks + 8 * quad;
                bh[ks] = ldg8b(&Bh_[off]);
                bl[ks] = ldg8b(&Bl_[off]);
            }
            vm_wait0();
            v4f acc[2] = {};
#pragma unroll
            for (int ks = 0; ks < 2; ++ks)
#pragma unroll
                for (int mt = 0; mt < 2; ++mt) {
                    acc[mt] = __builtin_amdgcn_mfma_f32_16x16x32_bf16(ah[mt][ks], bh[ks], acc[mt], 0, 0, 0);
                    acc[mt] = __builtin_amdgcn_mfma_f32_16x16x32_bf16(ah[mt][ks], bl[ks], acc[mt], 0, 0, 0);
                    acc[mt] = __builtin_amdgcn_mfma_f32_16x16x32_bf16(al[mt][ks], bh[ks], acc[mt], 0, 0, 0);
                }
#pragma unroll
            for (int mt = 0; mt < 2; ++mt)
#pragma unroll
                for (int r = 0; r < 4; ++r)
                    part[wv * 512 + (16 * mt + 4 * quad + r) * 16 + l16] = acc[mt][r];
            __syncthreads();
#pragma unroll
            for (int e = 0; e < 512; e += 256) {
                int ee = e + t;
                float v = part[ee] + part[512 + ee] + part[1024 + ee] + part[1536 + ee];
                int row = ee >> 4, col = ee & 15;
                unsigned short h = f2bf(v);
                unsigned short lo2 = f2bf(v - bf2f(h));
                int gidx = (ci + row) * C_DIM + cj + col;
                stgus_llc(&Dh[gidx], h);
                stgus_llc(&Dl[gidx], lo2);
            }
        }
        ++ph; gsync(bar, bid, ph);
        {   // -------- Phase B: 16x16 tile per block, P' = 1.5P - 0.5*T1@T2 --
            int ci = (bid >> 4) * 16, cj = (bid & 15) * 16;
            short8 ah[2], al[2], bh[2], bl[2];
#pragma unroll
            for (int ks = 0; ks < 2; ++ks) {
                int offa = (ci + l16) * C_DIM + kb + 32 * ks + 8 * quad;
                int offb = (cj + l16) * C_DIM + kb + 32 * ks + 8 * quad;
                ah[ks] = ldg8b(&T1h[offa]);
                al[ks] = ldg8b(&T1l[offa]);
                bh[ks] = ldg8b(&T2h[offb]);
                bl[ks] = ldg8b(&T2l[offb]);
            }
            vm_wait0();
            v4f acc = {};
#pragma unroll
            for (int ks = 0; ks < 2; ++ks) {
                acc = __builtin_amdgcn_mfma_f32_16x16x32_bf16(ah[ks], bh[ks], acc, 0, 0, 0);
                acc = __builtin_amdgcn_mfma_f32_16x16x32_bf16(ah[ks], bl[ks], acc, 0, 0, 0);
                acc = __builtin_amdgcn_mfma_f32_16x16x32_bf16(al[ks], bh[ks], acc, 0, 0, 0);
            }
#pragma unroll
            for (int r = 0; r < 4; ++r)
                part[wv * 256 + (4 * quad + r) * 16 + l16] = acc[r];
            __syncthreads();
            {
                float u = part[t] + part[256 + t] + part[512 + t] + part[768 + t];
                int row = t >> 4, col = t & 15;
                int gidx = (ci + row) * C_DIM + cj + col;
                unsigned hu = ldgus_llc(&Ph[gidx]);
                unsigned lu = ldgus_llc(&Pl[gidx]);
                vm_wait0();
                float p = bf2f((unsigned short)hu) + bf2f((unsigned short)lu);
                float v = 1.5f * p - 0.5f * u;
                unsigned short h = f2bf(v);
                unsigned short lo2 = f2bf(v - bf2f(h));
                stgus_llc(&Ph[gidx], h);
                stgus_llc(&Pl[gidx], lo2);
            }
        }
        ++ph; gsync(bar, bid, ph);
    }

    // ---- Phase 3: rot. M = (R@P)*s1 -> Mbf + moff. 16x16 tile per block.
    {
        int ci = (bid >> 4) * 16, cj = (bid & 15) * 16;
        short8 rh[2], rl[2], bh[2], bl[2];
#pragma unroll
        for (int ks = 0; ks < 2; ++ks) {
            const float* rp = &R[(ci + l16) * C_DIM + kb + 32 * ks + 8 * quad];
            f4 a0 = *(const f4*)rp;
            f4 a1 = *(const f4*)(rp + 4);
            uint2 h0, l0, h1, l1;
            split4v(a0, &h0, &l0);
            split4v(a1, &h1, &l1);
            S8U sh_; sh_.u[0] = h0.x; sh_.u[1] = h0.y; sh_.u[2] = h1.x; sh_.u[3] = h1.y;
            S8U sl_; sl_.u[0] = l0.x; sl_.u[1] = l0.y; sl_.u[2] = l1.x; sl_.u[3] = l1.y;
            rh[ks] = sh_.s;
            rl[ks] = sl_.s;
            int offb = (cj + l16) * C_DIM + kb + 32 * ks + 8 * quad;
            bh[ks] = ldg8b(&Ph[offb]);
            bl[ks] = ldg8b(&Pl[offb]);
        }
        vm_wait0();
        v4f acc = {};
#pragma unroll
        for (int ks = 0; ks < 2; ++ks) {
            acc = __builtin_amdgcn_mfma_f32_16x16x32_bf16(rh[ks], bh[ks], acc, 0, 0, 0);
            acc = __builtin_amdgcn_mfma_f32_16x16x32_bf16(rh[ks], bl[ks], acc, 0, 0, 0);
            acc = __builtin_amdgcn_mfma_f32_16x16x32_bf16(rl[ks], bh[ks], acc, 0, 0, 0);
        }
#pragma unroll
        for (int r = 0; r < 4; ++r)
            part[wv * 256 + (4 * quad + r) * 16 + l16] = acc[r];
        __syncthreads();
        float u = part[t] + part[256 + t] + part[512 + t] + part[768 + t];
        int row = t >> 4, col = t & 15;
        float val = u * s1;
        Mbf[(ci + row) * C_DIM + cj + col] = f2bf(val);        // plain store: next-kernel boundary flushes
        float contrib = val * (musum[cj + col] * (1.0f / M_TOTAL));
        __syncthreads();
        part[t] = contrib;
        __syncthreads();
        if ((t & 15) == 0) {
            float s = 0.f;
#pragma unroll
            for (int i = 0; i < 16; ++i) s += part[t + i];
            atomicAdd(&moff[ci + (t >> 4)], s);
        }
    }
}

// ---------------------------------------------------------------------------
// Kernel 6: out[n,d,hw] = sum_c Mbf[d,c]*Xbf[n,c,hw] - moff[d]  via MFMA.
// grid (8 hw-tiles, 64 n): block computes FULL d=256 x 128 hw -> Xbf read ONCE.
// 4 waves 2x2: wave covers 128 d x 64 hw (mt 0..8, nt 0..4).
__global__ __launch_bounds__(256)
void out_mfma(const unsigned short* __restrict__ Xbf,
              const unsigned short* __restrict__ Mbf,
              const float* __restrict__ moff, float* __restrict__ out) {
    int hwb = blockIdx.x * 128;
    int n   = blockIdx.y;
    int t = threadIdx.x, wave = t >> 6, lane = t & 63;
    int wy = wave >> 1, wx = wave & 1, quad = lane >> 4, l16 = lane & 15;

    __shared__ __align__(16) unsigned short Asm[256 * 40];
    __shared__ __align__(16) unsigned short Bsm[128 * 34];
    __shared__ __align__(16) float Ep[4 * 16 * 68];   // per-wave 16x64 epilogue buffer

    v4f acc[8][4] = {};
    const unsigned short* Xn = Xbf + (((size_t)n * C_DIM) << 10);

    for (int kb = 0; kb < 256; kb += 32) {
        __syncthreads();
#pragma unroll
        for (int i = 0; i < 4; ++i) {
            int a = t + 256 * i;
            int row = a >> 2, c8 = a & 3;
            *(uint4*)(&Asm[row * 40 + 8 * c8]) =
                *(const uint4*)(&Mbf[row * C_DIM + kb + 8 * c8]);
        }
#pragma unroll
        for (int i = 0; i < 16; ++i) {
            int idx = t + 256 * i;
            int hw = idx & 127, crow = idx >> 7;
            Bsm[hw * 34 + crow] = Xn[(((size_t)(kb + crow)) << 10) + hwb + hw];
        }
        __syncthreads();

        short8 af[8], bfr[4];
#pragma unroll
        for (int mt = 0; mt < 8; ++mt)
            af[mt] = *(const short8*)(&Asm[(128 * wy + 16 * mt + l16) * 40 + 8 * quad]);
#pragma unroll
        for (int nt = 0; nt < 4; ++nt) {
            union { short8 s; unsigned u[4]; } tmp;
            const unsigned short* bp = &Bsm[(64 * wx + 16 * nt + l16) * 34 + 8 * quad];
            tmp.u[0] = *(const unsigned*)(bp + 0);
            tmp.u[1] = *(const unsigned*)(bp + 2);
            tmp.u[2] = *(const unsigned*)(bp + 4);
            tmp.u[3] = *(const unsigned*)(bp + 6);
            bfr[nt] = tmp.s;
        }
#pragma unroll
        for (int mt = 0; mt < 8; ++mt)
#pragma unroll
            for (int nt = 0; nt < 4; ++nt)
                acc[mt][nt] = __builtin_amdgcn_mfma_f32_16x16x32_bf16(af[mt], bfr[nt], acc[mt][nt], 0, 0, 0);
    }

    float* W = &Ep[wave * 16 * 68];
#pragma unroll
    for (int mt = 0; mt < 8; ++mt) {
#pragma unroll
        for (int r = 0; r < 4; ++r) {
            float off = moff[128 * wy + 16 * mt + 4 * quad + r];
#pragma unroll
            for (int nt = 0; nt < 4; ++nt)
                W[(4 * quad + r) * 68 + 16 * nt + l16] = acc[mt][nt][r] - off;
        }
        __syncthreads();   // orders wave-local LDS ops; uniform across block
#pragma unroll
        for (int j = 0; j < 4; ++j) {
            int row = 4 * j + quad;
            float4 v = *(const float4*)&W[row * 68 + 4 * l16];
            int d = 128 * wy + 16 * mt + row;
            int hw = hwb + 64 * wx + 4 * l16;
            *(float4*)&out[(((size_t)(n * C_DIM + d)) << 10) + hw] = v;
        }
        __syncthreads();
    }
}

// ---------------------------------------------------------------------------
extern "C" void kernel_launch(void* const* d_in, const int* in_sizes, int n_in,
                              void* d_out, int out_size, void* d_ws, size_t ws_size,
                              hipStream_t stream) {
    const float* X = (const float*)d_in[0];        // (64,256,32,32)
    const float* R = (const float*)d_in[1];        // (1,256,256)
    float* out = (float*)d_out;
    float* ws  = (float*)d_ws;

    float* musum = ws;                         // [0,256)
    float* moff  = ws + 256;                   // [256,512)
    unsigned* bar = (unsigned*)(ws + 512);     // [512,1056): 17 counters, 128B apart
    float* G     = ws + 1088;                  // 65536 fp32 (raw gram, 3 tiles)
    unsigned short* Ph  = (unsigned short*)(G + 65536);   // 9 x 65536 ushort arrays
    unsigned short* Pl  = Ph  + 65536;
    unsigned short* Sh  = Pl  + 65536;
    unsigned short* Sl  = Sh  + 65536;
    unsigned short* T1h = Sl  + 65536;
    unsigned short* T1l = T1h + 65536;
    unsigned short* T2h = T1l + 65536;
    unsigned short* T2l = T2h + 65536;
    unsigned short* Mbf = T2l + 65536;
    unsigned short* Xbf = Mbf + 65536;                    // 16M ushort (32 MB)

    hipMemsetAsync(ws, 0, (1088 + 65536) * sizeof(float), stream);

    prepass_kernel<<<4096, 256, 0, stream>>>(X, Xbf, musum);
    gram_mfma<<<dim3(3, 128), 512, 0, stream>>>(Xbf, G);

    ns_persist<<<256, 256, 0, stream>>>(G, musum, R, Ph, Pl, Sh, Sl,
                                        T1h, T1l, T2h, T2l, Mbf, moff, bar);

    out_mfma<<<dim3(8, 64), 256, 0, stream>>>(Xbf, Mbf, moff, out);
}